// Round 6
// baseline (1775.415 us; speedup 1.0000x reference)
//
#include <hip/hip_runtime.h>
#include <hip/hip_bf16.h>

#define H 64
#define PADW 88    // old-path bf16 plane stride (shorts)
#define PADU 136   // old-path bf16 plane stride K=128 (shorts)
#define PADT 68    // old-path f32 transpose-buffer stride (floats)
#define BSTR 68    // batch/tbuf row stride (dwords): 16B-aligned, mild bank alias

typedef __attribute__((ext_vector_type(8))) short short8;
typedef __attribute__((ext_vector_type(4))) float floatx4;
typedef __attribute__((ext_vector_type(4))) unsigned int uintx4;

#define MFMA(a, b, c) __builtin_amdgcn_mfma_f32_16x16x32_bf16(a, b, c, 0, 0, 0)

__device__ __forceinline__ float bf2f(short s) {
  union { unsigned int u; float f; } v;
  v.u = ((unsigned int)(unsigned short)s) << 16;
  return v.f;
}
__device__ __forceinline__ short f2bf(float f) {
  union { float f; unsigned int u; } v; v.f = f;
  unsigned int r = v.u + 0x7fffu + ((v.u >> 16) & 1u);  // RNE
  return (short)(r >> 16);
}
__device__ __forceinline__ void split2(float v, short& hi, short& lo) {
  hi = f2bf(v);
  lo = f2bf(v - bf2f(hi));
}
__device__ __forceinline__ unsigned int packhl(float v) {
  short hi, lo; split2(v, hi, lo);
  return ((unsigned int)(unsigned short)hi << 16) | (unsigned int)(unsigned short)lo;
}
__device__ __forceinline__ float ldf(const void* p, long idx, bool isf32) {
  return isf32 ? ((const float*)p)[idx] : bf2f(((const short*)p)[idx]);
}
// unpack 8 packed (hi<<16|lo) dwords into two bf16 short8 fragments
__device__ __forceinline__ void unpack8(const unsigned int* p, short8& hi, short8& lo) {
  unsigned int u[8];
  *(uintx4*)(u) = *(const uintx4*)(p);
  *(uintx4*)(u + 4) = *(const uintx4*)(p + 4);
#pragma unroll
  for (int j = 0; j < 8; ++j) { hi[j] = (short)(u[j] >> 16); lo[j] = (short)(u[j] & 0xffff); }
}

// dtype probe
__global__ void k_probe(const short* __restrict__ x, int* __restrict__ flag) {
  __shared__ int cnt;
  if (threadIdx.x == 0) cnt = 0;
  __syncthreads();
  short s = x[threadIdx.x];
  int e = (s >> 7) & 0xFF;
  int insane = (e != 0 && (e < 100 || e > 140)) ? 1 : 0;
  atomicAdd(&cnt, insane);
  __syncthreads();
  if (threadIdx.x == 0) *flag = (cnt > 64) ? 1 : 0;  // 1 = f32 inputs
}

// h0 = relu(x @ w_in + b_in) -> hi/lo planes
__global__ void k_input2(const void* __restrict__ x, const void* __restrict__ w,
                         const void* __restrict__ b, short* __restrict__ hhi,
                         short* __restrict__ hlo, const int* __restrict__ flag, int N) {
  bool isf32 = (*flag != 0);
  int idx = blockIdx.x * 256 + threadIdx.x;
  if (idx >= N * H) return;
  int v = idx >> 6, k = idx & 63;
  float acc = ldf(b, k, isf32);
#pragma unroll
  for (int d = 0; d < 3; ++d)
    acc += ldf(x, (long)v * 3 + d, isf32) * ldf(w, d * 64 + k, isf32);
  float r = fmaxf(acc, 0.f);
  short hi, lo; split2(r, hi, lo);
  hhi[idx] = hi; hlo[idx] = lo;
}

// ---------------- CSR build (counting sort by dst) ----------------

__global__ void k_hist(const int* __restrict__ dstI, int* __restrict__ deg, int E) {
  int e = blockIdx.x * 256 + threadIdx.x;
  if (e < E) atomicAdd(&deg[dstI[e]], 1);
}

__global__ void k_scan_local(const int* __restrict__ deg, int* __restrict__ rowptr,
                             int* __restrict__ bsum, int N) {
  __shared__ int s[256];
  int tid = threadIdx.x;
  int base = blockIdx.x * 1024 + tid * 4;
  int v0 = (base + 0 < N) ? deg[base + 0] : 0;
  int v1 = (base + 1 < N) ? deg[base + 1] : 0;
  int v2 = (base + 2 < N) ? deg[base + 2] : 0;
  int v3 = (base + 3 < N) ? deg[base + 3] : 0;
  int tsum = v0 + v1 + v2 + v3;
  s[tid] = tsum;
  __syncthreads();
  for (int off = 1; off < 256; off <<= 1) {
    int x = (tid >= off) ? s[tid - off] : 0;
    __syncthreads();
    s[tid] += x;
    __syncthreads();
  }
  int excl = s[tid] - tsum;
  if (base + 0 < N) rowptr[base + 0] = excl;
  if (base + 1 < N) rowptr[base + 1] = excl + v0;
  if (base + 2 < N) rowptr[base + 2] = excl + v0 + v1;
  if (base + 3 < N) rowptr[base + 3] = excl + v0 + v1 + v2;
  if (tid == 255) bsum[blockIdx.x] = s[255];
}

__global__ void k_scan_block(const int* __restrict__ bsum, int* __restrict__ bexcl, int nb) {
  __shared__ int s[256];
  int tid = threadIdx.x;
  int v = (tid < nb) ? bsum[tid] : 0;
  s[tid] = v;
  __syncthreads();
  for (int off = 1; off < 256; off <<= 1) {
    int x = (tid >= off) ? s[tid - off] : 0;
    __syncthreads();
    s[tid] += x;
    __syncthreads();
  }
  bexcl[tid] = s[tid] - v;
}

__global__ void k_scan_add(int* __restrict__ rowptr, int* __restrict__ cursor,
                           const int* __restrict__ bexcl, int N, int E) {
  int i = blockIdx.x * 256 + threadIdx.x;
  if (i < N) {
    int v = rowptr[i] + bexcl[i >> 10];
    rowptr[i] = v;
    cursor[i] = v;
  }
  if (i == N) rowptr[N] = E;
}

__global__ void k_scatter(const int* __restrict__ srcI, const int* __restrict__ dstI,
                          int* __restrict__ cursor, int* __restrict__ srcS, int E) {
  int e = blockIdx.x * 256 + threadIdx.x;
  if (e >= E) return;
  int d = dstI[e];
  int p = atomicAdd(&cursor[d], 1);
  srcS[p] = srcI[e];
}

// ---------------- persistent message kernel v3 ----------------
// Work-stealing over 16-node batches (atomic ctr). Per chunk: hi-only h gather
// (2x16B loads), 16 MFMA GEMM1 (W1 hi+lo in regs). GEMM2 once per batch from
// packed sumP (linearity of W2). agg written as packed hi|lo uint.
__global__ __launch_bounds__(256) void k_msg2(
    const short* __restrict__ hhi,
    const int* __restrict__ rowptr, const int* __restrict__ srcS,
    const void* __restrict__ W1, const void* __restrict__ B1,
    const void* __restrict__ W2, const void* __restrict__ B2,
    long oW, long oB, unsigned int* __restrict__ agg, const int* __restrict__ flag,
    int N, int* __restrict__ ctr) {
  __shared__ unsigned int wbuf[4096];          // staged W1 -> regs, then restaged W2
  __shared__ unsigned int batch[4][16 * BSTR]; // per-wave sumP rows (packed hi|lo)
  __shared__ int degs[4][16];
  __shared__ float b1s[64], b2s[64];

  bool isf32 = (*flag != 0);
  int tid = threadIdx.x;
  // stage W1 fragment-major (B-frag: row=(t*2+c)*64 + (q*16+n&15))
  for (int idx = tid; idx < 4096; idx += 256) {
    int k = idx >> 6, n = idx & 63;  // W[k=in][n=out] row-major
    int t = n >> 4, m2 = n & 15, c = k >> 5, q2 = (k >> 3) & 3, j = k & 7;
    wbuf[(((t * 2 + c) * 64) + (q2 * 16 + m2)) * 8 + j] = packhl(ldf(W1, oW + idx, isf32));
  }
  if (tid < 64) { b1s[tid] = ldf(B1, oB + tid, isf32); b2s[tid] = ldf(B2, oB + tid, isf32); }
  __syncthreads();

  const int wave = tid >> 6, lane = tid & 63;
  const int m = lane & 15, q = lane >> 4;

  // hoist W1 fragments into registers
  short8 w1hiR[4][2], w1loR[4][2];
#pragma unroll
  for (int t = 0; t < 4; ++t)
#pragma unroll
    for (int c = 0; c < 2; ++c)
      unpack8(&wbuf[(((t * 2 + c) * 64) + lane) * 8], w1hiR[t][c], w1loR[t][c]);
  float b1r[4];
#pragma unroll
  for (int t = 0; t < 4; ++t) b1r[t] = b1s[16 * t + m];
  __syncthreads();
  // restage W2 into the same buffer
  for (int idx = tid; idx < 4096; idx += 256) {
    int k = idx >> 6, n = idx & 63;
    int t = n >> 4, m2 = n & 15, c = k >> 5, q2 = (k >> 3) & 3, j = k & 7;
    wbuf[(((t * 2 + c) * 64) + (q2 * 16 + m2)) * 8 + j] = packhl(ldf(W2, oW + idx, isf32));
  }
  __syncthreads();

  const int nBatch = (N + 15) >> 4;
  unsigned int* bb_buf = batch[wave];

  for (;;) {
    int bb;
    if (lane == 0) bb = atomicAdd(ctr, 1);
    bb = __shfl(bb, 0);
    if (bb >= nBatch) break;
    const int nb0 = bb * 16;

    for (int b = 0; b < 16; ++b) {
      int node = nb0 + b;
      int rs = 0, re = 0;
      if (node < N) { rs = rowptr[node]; re = rowptr[node + 1]; }
      floatx4 sum[4];
#pragma unroll
      for (int t = 0; t < 4; ++t) sum[t] = (floatx4){0.f, 0.f, 0.f, 0.f};

      for (int base = rs; base < re; base += 16) {
        int e = base + m;
        int ec = e < re ? e : re - 1;
        int sv = srcS[ec];
        const short* hbh = hhi + (long)sv * H;
        short8 hh0 = *(const short8*)(hbh + 8 * q);
        short8 hh1 = *(const short8*)(hbh + 32 + 8 * q);

        floatx4 p4[4];
#pragma unroll
        for (int t = 0; t < 4; ++t) p4[t] = (floatx4){0.f, 0.f, 0.f, 0.f};
#pragma unroll
        for (int t = 0; t < 4; ++t) {
          p4[t] = MFMA(hh0, w1hiR[t][0], p4[t]);
          p4[t] = MFMA(hh1, w1hiR[t][1], p4[t]);
          p4[t] = MFMA(hh0, w1loR[t][0], p4[t]);
          p4[t] = MFMA(hh1, w1loR[t][1], p4[t]);
        }
#pragma unroll
        for (int r = 0; r < 4; ++r) {
          bool ok = (base + 4 * q + r) < re;
#pragma unroll
          for (int t = 0; t < 4; ++t) {
            float v = fmaxf(p4[t][r] + b1r[t], 0.f);
            sum[t][r] += ok ? v : 0.f;
          }
        }
      }
      float sf[4];
#pragma unroll
      for (int t = 0; t < 4; ++t) {
        float s = sum[t][0] + sum[t][1] + sum[t][2] + sum[t][3];
        s += __shfl_xor(s, 16);
        s += __shfl_xor(s, 32);
        sf[t] = s;
      }
      float sel = (q == 0) ? sf[0] : (q == 1) ? sf[1] : (q == 2) ? sf[2] : sf[3];
      bb_buf[b * BSTR + lane] = packhl(sel);
      if (lane == 0) degs[wave][b] = re - rs;
    }
    // batch GEMM2: sumP(16x64) @ W2
    short8 ahi[2], alo[2];
#pragma unroll
    for (int c = 0; c < 2; ++c)
      unpack8(&bb_buf[m * BSTR + 32 * c + 8 * q], ahi[c], alo[c]);

    floatx4 m4[4];
#pragma unroll
    for (int t = 0; t < 4; ++t) m4[t] = (floatx4){0.f, 0.f, 0.f, 0.f};
#pragma unroll
    for (int t = 0; t < 4; ++t) {
      short8 b0h, b0l, b1h, b1l;
      unpack8(&wbuf[(((t * 2 + 0) * 64) + lane) * 8], b0h, b0l);
      unpack8(&wbuf[(((t * 2 + 1) * 64) + lane) * 8], b1h, b1l);
      m4[t] = MFMA(ahi[0], b0h, m4[t]);
      m4[t] = MFMA(ahi[1], b1h, m4[t]);
      m4[t] = MFMA(alo[0], b0h, m4[t]);
      m4[t] = MFMA(alo[1], b1h, m4[t]);
      m4[t] = MFMA(ahi[0], b0l, m4[t]);
      m4[t] = MFMA(ahi[1], b1l, m4[t]);
    }
#pragma unroll
    for (int r = 0; r < 4; ++r) {
      int nd = nb0 + 4 * q + r;
      if (nd < N) {
        float dv = (float)degs[wave][4 * q + r];
#pragma unroll
        for (int t = 0; t < 4; ++t) {
          int col = 16 * t + m;
          agg[(long)nd * H + col] = packhl(m4[t][r] + dv * b2s[col]);
        }
      }
    }
  }
}

// ---------------- persistent update kernel v3 ----------------
// Work-stealing over 16-node batches; weights staged once per block,
// fragment-major packed hi|lo; agg read as packed uint; in-place h update.
__global__ __launch_bounds__(256) void k_upd3(
    short* __restrict__ hhi, short* __restrict__ hlo, const unsigned int* __restrict__ agg,
    const void* __restrict__ W1, const void* __restrict__ B1,
    const void* __restrict__ W2, const void* __restrict__ B2,
    const void* __restrict__ G, const void* __restrict__ Bb,
    const void* __restrict__ Mm, const void* __restrict__ Vv,
    long oU, long oW, long oB, const int* __restrict__ flag, int N,
    int* __restrict__ ctr) {
  __shared__ unsigned int u1p[8192];           // W1 (128x64) packed frag-major, 32KB
  __shared__ unsigned int u2p[4096];           // W2 (64x64), 16KB
  __shared__ unsigned int tb[4][16 * BSTR];    // per-wave P rows (packed), 17.4KB
  __shared__ float b1s[64], b2s[64], scl[64], sft[64];

  bool isf32 = (*flag != 0);
  int tid = threadIdx.x;
  for (int idx = tid; idx < 8192; idx += 256) {
    int k = idx >> 6, n = idx & 63;  // k=in(0..127), n=out
    int t = n >> 4, m2 = n & 15, c = k >> 5, q2 = (k >> 3) & 3, j = k & 7;
    u1p[(((t * 4 + c) * 64) + (q2 * 16 + m2)) * 8 + j] = packhl(ldf(W1, oU + idx, isf32));
  }
  for (int idx = tid; idx < 4096; idx += 256) {
    int k = idx >> 6, n = idx & 63;
    int t = n >> 4, m2 = n & 15, c = k >> 5, q2 = (k >> 3) & 3, j = k & 7;
    u2p[(((t * 2 + c) * 64) + (q2 * 16 + m2)) * 8 + j] = packhl(ldf(W2, oW + idx, isf32));
  }
  if (tid < 64) {
    b1s[tid] = ldf(B1, oB + tid, isf32);
    b2s[tid] = ldf(B2, oB + tid, isf32);
    float s = ldf(G, oB + tid, isf32) * rsqrtf(ldf(Vv, oB + tid, isf32) + 1e-5f);
    scl[tid] = s;
    sft[tid] = ldf(Bb, oB + tid, isf32) - ldf(Mm, oB + tid, isf32) * s;
  }
  __syncthreads();

  const int wave = tid >> 6, lane = tid & 63;
  const int m = lane & 15, q = lane >> 4;
  unsigned int* tbw = tb[wave];
  const int nBatch = (N + 15) >> 4;

  for (;;) {
    int bb;
    if (lane == 0) bb = atomicAdd(ctr, 1);
    bb = __shfl(bb, 0);
    if (bb >= nBatch) break;
    const int nb0 = bb * 16;
    int node = nb0 + m;
    int nc = node < N ? node : N - 1;

    // A fragments: [h | agg], k = c*32 + 8q + j
    short8 fhi[4], flo[4];
    fhi[0] = *(const short8*)(hhi + (long)nc * H + 8 * q);
    fhi[1] = *(const short8*)(hhi + (long)nc * H + 32 + 8 * q);
    flo[0] = *(const short8*)(hlo + (long)nc * H + 8 * q);
    flo[1] = *(const short8*)(hlo + (long)nc * H + 32 + 8 * q);
    unpack8(&agg[(long)nc * H + 8 * q], fhi[2], flo[2]);
    unpack8(&agg[(long)nc * H + 32 + 8 * q], fhi[3], flo[3]);

    floatx4 acc[4];
#pragma unroll
    for (int t = 0; t < 4; ++t) acc[t] = (floatx4){0.f, 0.f, 0.f, 0.f};
#pragma unroll
    for (int t = 0; t < 4; ++t) {
#pragma unroll
      for (int c = 0; c < 4; ++c) {
        short8 whi, wlo;
        unpack8(&u1p[(((t * 4 + c) * 64) + lane) * 8], whi, wlo);
        acc[t] = MFMA(fhi[c], whi, acc[t]);
        acc[t] = MFMA(flo[c], whi, acc[t]);
        acc[t] = MFMA(fhi[c], wlo, acc[t]);
      }
    }

    // P -> per-wave LDS (packed), then A-frag for GEMM2
#pragma unroll
    for (int t = 0; t < 4; ++t) {
      int col = 16 * t + m;
      float bbv = b1s[col];
#pragma unroll
      for (int r = 0; r < 4; ++r)
        tbw[(4 * q + r) * BSTR + col] = packhl(fmaxf(acc[t][r] + bbv, 0.f));
    }
    short8 thi[2], tlo[2];
    unpack8(&tbw[m * BSTR + 8 * q], thi[0], tlo[0]);
    unpack8(&tbw[m * BSTR + 32 + 8 * q], thi[1], tlo[1]);

    floatx4 mac[4];
#pragma unroll
    for (int t = 0; t < 4; ++t) mac[t] = (floatx4){0.f, 0.f, 0.f, 0.f};
#pragma unroll
    for (int t = 0; t < 4; ++t) {
#pragma unroll
      for (int c = 0; c < 2; ++c) {
        short8 whi, wlo;
        unpack8(&u2p[(((t * 2 + c) * 64) + lane) * 8], whi, wlo);
        mac[t] = MFMA(thi[c], whi, mac[t]);
        mac[t] = MFMA(tlo[c], whi, mac[t]);
        mac[t] = MFMA(thi[c], wlo, mac[t]);
      }
    }

#pragma unroll
    for (int t = 0; t < 4; ++t) {
      int col = 16 * t + m;
      float bbv = b2s[col], ss = scl[col], ff = sft[col];
#pragma unroll
      for (int r = 0; r < 4; ++r) {
        int nrow = nb0 + 4 * q + r;
        if (nrow < N) {
          long el = (long)nrow * H + col;
          float hv = (mac[t][r] + bbv) * ss + ff;
          float ho = bf2f(hhi[el]) + bf2f(hlo[el]);
          float hn = fmaxf(hv + ho, 0.f);
          short hi2, lo2; split2(hn, hi2, lo2);
          hhi[el] = hi2; hlo[el] = lo2;
        }
      }
    }
  }
}

// readout from hi/lo planes
__global__ __launch_bounds__(256) void k_out2(
    const short* __restrict__ hhi, const short* __restrict__ hlo,
    const void* __restrict__ W1, const void* __restrict__ B1,
    const void* __restrict__ W2, const void* __restrict__ B2,
    void* __restrict__ out, const int* __restrict__ flag, int NQ) {
  __shared__ float w1s[64 * 32];
  __shared__ float b1sh[32], w2s[32];
  bool isf32 = (*flag != 0);
  int tid = threadIdx.x;
  for (int idx = tid; idx < 2048; idx += 256) w1s[idx] = ldf(W1, idx, isf32);
  if (tid < 32) { b1sh[tid] = ldf(B1, tid, isf32); w2s[tid] = ldf(W2, tid, isf32); }
  __syncthreads();
  int v = blockIdx.x * 256 + tid;
  if (v >= NQ) return;
  float hr[64];
#pragma unroll
  for (int j = 0; j < 64; ++j)
    hr[j] = bf2f(hhi[(long)v * H + j]) + bf2f(hlo[(long)v * H + j]);
  float accum = ldf(B2, 0, isf32);
#pragma unroll 4
  for (int k = 0; k < 32; ++k) {
    float t = b1sh[k];
#pragma unroll
    for (int j = 0; j < 64; ++j) t += hr[j] * w1s[j * 32 + k];
    accum += fmaxf(t, 0.f) * w2s[k];
  }
  if (isf32) ((float*)out)[v] = accum;
  else ((short*)out)[v] = f2bf(accum);
}

// ---------------- old fallback path (round-3, f32 h) ----------------

__global__ void k_input(const void* __restrict__ x, const void* __restrict__ w,
                        const void* __restrict__ b, float* __restrict__ h,
                        const int* __restrict__ flag, int N) {
  bool isf32 = (*flag != 0);
  int idx = blockIdx.x * 256 + threadIdx.x;
  if (idx >= N * H) return;
  int v = idx >> 6, k = idx & 63;
  float acc = ldf(b, k, isf32);
#pragma unroll
  for (int d = 0; d < 3; ++d)
    acc += ldf(x, (long)v * 3 + d, isf32) * ldf(w, d * 64 + k, isf32);
  h[idx] = fmaxf(acc, 0.f);
}

template <bool AF32>
__global__ __launch_bounds__(256) void k_msg(
    const float* __restrict__ h, const int* __restrict__ srcI, const int* __restrict__ dstI,
    const void* __restrict__ W1, const void* __restrict__ B1,
    const void* __restrict__ W2, const void* __restrict__ B2,
    long oW, long oB,
    void* __restrict__ aggv, const int* __restrict__ flag, int E) {
  __shared__ short w1hi[64 * PADW], w1lo[64 * PADW];
  __shared__ short w2hi[64 * PADW], w2lo[64 * PADW];
  __shared__ float b1s[64], b2s[64];
  __shared__ float tbuf[4][16 * PADT];

  bool isf32 = (*flag != 0);
  int tid = threadIdx.x;
  for (int idx = tid; idx < 4096; idx += 256) {
    int j = idx >> 6, k = idx & 63;
    short hi, lo;
    split2(ldf(W1, oW + idx, isf32), hi, lo);
    w1hi[k * PADW + j] = hi; w1lo[k * PADW + j] = lo;
    split2(ldf(W2, oW + idx, isf32), hi, lo);
    w2hi[k * PADW + j] = hi; w2lo[k * PADW + j] = lo;
  }
  if (tid < 64) {
    b1s[tid] = ldf(B1, oB + tid, isf32);
    b2s[tid] = ldf(B2, oB + tid, isf32);
  }
  __syncthreads();

  const int wave = tid >> 6, lane = tid & 63;
  const int m = lane & 15, quad = lane >> 4;
  const int eBase = (blockIdx.x * 4 + wave) * 16;

  int e = eBase + m;
  int ec = e < E ? e : E - 1;
  int sv = srcI[ec];
  int dv = dstI[ec];

  const float* hrow = h + (long)sv * H;
  float av[16];
  *(floatx4*)(av + 0)  = *(const floatx4*)(hrow + quad * 8);
  *(floatx4*)(av + 4)  = *(const floatx4*)(hrow + quad * 8 + 4);
  *(floatx4*)(av + 8)  = *(const floatx4*)(hrow + 32 + quad * 8);
  *(floatx4*)(av + 12) = *(const floatx4*)(hrow + 32 + quad * 8 + 4);
  short8 ahi0, alo0, ahi1, alo1;
#pragma unroll
  for (int j = 0; j < 8; ++j) {
    short hi, lo;
    split2(av[j], hi, lo);     ahi0[j] = hi; alo0[j] = lo;
    split2(av[8 + j], hi, lo); ahi1[j] = hi; alo1[j] = lo;
  }

  floatx4 acc[4];
#pragma unroll
  for (int t = 0; t < 4; ++t) acc[t] = (floatx4){0.f, 0.f, 0.f, 0.f};
#pragma unroll
  for (int t = 0; t < 4; ++t) {
    const short* whi = &w1hi[(t * 16 + m) * PADW + quad * 8];
    const short* wlo = &w1lo[(t * 16 + m) * PADW + quad * 8];
    acc[t] = MFMA(ahi0, *(const short8*)(whi), acc[t]);
    acc[t] = MFMA(ahi1, *(const short8*)(whi + 32), acc[t]);
    acc[t] = MFMA(alo0, *(const short8*)(whi), acc[t]);
    acc[t] = MFMA(alo1, *(const short8*)(whi + 32), acc[t]);
    acc[t] = MFMA(ahi0, *(const short8*)(wlo), acc[t]);
    acc[t] = MFMA(ahi1, *(const short8*)(wlo + 32), acc[t]);
  }

  float* tbf = tbuf[wave];
#pragma unroll
  for (int t = 0; t < 4; ++t) {
    int col = t * 16 + m;
    float bb = b1s[col];
#pragma unroll
    for (int r = 0; r < 4; ++r)
      tbf[(quad * 4 + r) * PADT + col] = fmaxf(acc[t][r] + bb, 0.f);
  }
  __syncthreads();

  *(floatx4*)(av + 0)  = *(const floatx4*)(&tbf[m * PADT + quad * 8]);
  *(floatx4*)(av + 4)  = *(const floatx4*)(&tbf[m * PADT + quad * 8 + 4]);
  *(floatx4*)(av + 8)  = *(const floatx4*)(&tbf[m * PADT + 32 + quad * 8]);
  *(floatx4*)(av + 12) = *(const floatx4*)(&tbf[m * PADT + 32 + quad * 8 + 4]);
#pragma unroll
  for (int j = 0; j < 8; ++j) {
    short hi, lo;
    split2(av[j], hi, lo);     ahi0[j] = hi; alo0[j] = lo;
    split2(av[8 + j], hi, lo); ahi1[j] = hi; alo1[j] = lo;
  }

  floatx4 mac[4];
#pragma unroll
  for (int t = 0; t < 4; ++t) mac[t] = (floatx4){0.f, 0.f, 0.f, 0.f};
#pragma unroll
  for (int t = 0; t < 4; ++t) {
    const short* whi = &w2hi[(t * 16 + m) * PADW + quad * 8];
    const short* wlo = &w2lo[(t * 16 + m) * PADW + quad * 8];
    mac[t] = MFMA(ahi0, *(const short8*)(whi), mac[t]);
    mac[t] = MFMA(ahi1, *(const short8*)(whi + 32), mac[t]);
    mac[t] = MFMA(alo0, *(const short8*)(whi), mac[t]);
    mac[t] = MFMA(alo1, *(const short8*)(whi + 32), mac[t]);
    mac[t] = MFMA(ahi0, *(const short8*)(wlo), mac[t]);
    mac[t] = MFMA(ahi1, *(const short8*)(wlo + 32), mac[t]);
  }

  float* aggF = (float*)aggv;
  short* aggS = (short*)aggv;
#pragma unroll
  for (int t = 0; t < 4; ++t) {
    int col = t * 16 + m;
    float bb = b2s[col];
#pragma unroll
    for (int r = 0; r < 4; ++r) {
      int row = quad * 4 + r;
      int er = eBase + row;
      int dr = __shfl(dv, row);
      float v = mac[t][r] + bb;
      if (AF32) {
        if (er < E) atomicAdd(&aggF[(long)dr * H + col], v);
      } else {
        float v2 = __shfl_down(v, 1);
        if (((m & 1) == 0) && er < E) {
          unsigned int pk = ((unsigned int)(unsigned short)f2bf(v2) << 16) |
                            (unsigned int)(unsigned short)f2bf(v);
          unsafeAtomicAdd((__hip_bfloat162*)&aggS[(long)dr * H + col],
                          *(__hip_bfloat162*)&pk);
        }
      }
    }
  }
}

template <bool AF32>
__global__ __launch_bounds__(256) void k_upd(
    const float* __restrict__ h, const void* __restrict__ aggv,
    const void* __restrict__ W1, const void* __restrict__ B1,
    const void* __restrict__ W2, const void* __restrict__ B2,
    const void* __restrict__ G, const void* __restrict__ Bb,
    const void* __restrict__ Mm, const void* __restrict__ Vv,
    long oU, long oW, long oB,
    float* __restrict__ hout, const int* __restrict__ flag, int N) {
  __shared__ short w1hi[64 * PADU], w1lo[64 * PADU];
  __shared__ short w2hi[64 * PADW], w2lo[64 * PADW];
  __shared__ float b1s[64], b2s[64], scl[64], sft[64];
  __shared__ float tbuf[4][16 * PADT];

  bool isf32 = (*flag != 0);
  int tid = threadIdx.x;
  for (int idx = tid; idx < 8192; idx += 256) {
    int j = idx >> 6, k = idx & 63;
    short hi, lo;
    split2(ldf(W1, oU + idx, isf32), hi, lo);
    w1hi[k * PADU + j] = hi; w1lo[k * PADU + j] = lo;
  }
  for (int idx = tid; idx < 4096; idx += 256) {
    int j = idx >> 6, k = idx & 63;
    short hi, lo;
    split2(ldf(W2, oW + idx, isf32), hi, lo);
    w2hi[k * PADW + j] = hi; w2lo[k * PADW + j] = lo;
  }
  if (tid < 64) {
    b1s[tid] = ldf(B1, oB + tid, isf32);
    b2s[tid] = ldf(B2, oB + tid, isf32);
    float s = ldf(G, oB + tid, isf32) * rsqrtf(ldf(Vv, oB + tid, isf32) + 1e-5f);
    scl[tid] = s;
    sft[tid] = ldf(Bb, oB + tid, isf32) - ldf(Mm, oB + tid, isf32) * s;
  }
  __syncthreads();

  const int wave = tid >> 6, lane = tid & 63;
  const int m = lane & 15, quad = lane >> 4;
  const int nBase = (blockIdx.x * 4 + wave) * 16;
  int node = nBase + m;
  int nc = node < N ? node : N - 1;

  float av[16];
  const float* hrow = h + (long)nc * H;
  *(floatx4*)(av + 0)  = *(const floatx4*)(hrow + quad * 8);
  *(floatx4*)(av + 4)  = *(const floatx4*)(hrow + quad * 8 + 4);
  *(floatx4*)(av + 8)  = *(const floatx4*)(hrow + 32 + quad * 8);
  *(floatx4*)(av + 12) = *(const floatx4*)(hrow + 32 + quad * 8 + 4);
  float gv[16];
  if (AF32) {
    const float* arow = (const float*)aggv + (long)nc * H;
    *(floatx4*)(gv + 0)  = *(const floatx4*)(arow + quad * 8);
    *(floatx4*)(gv + 4)  = *(const floatx4*)(arow + quad * 8 + 4);
    *(floatx4*)(gv + 8)  = *(const floatx4*)(arow + 32 + quad * 8);
    *(floatx4*)(gv + 12) = *(const floatx4*)(arow + 32 + quad * 8 + 4);
  } else {
    const short* arow = (const short*)aggv + (long)nc * H;
#pragma unroll
    for (int j = 0; j < 8; ++j) {
      gv[j] = bf2f(arow[quad * 8 + j]);
      gv[8 + j] = bf2f(arow[32 + quad * 8 + j]);
    }
  }
  short8 fhi[4], flo[4];
#pragma unroll
  for (int j = 0; j < 8; ++j) {
    short hi, lo;
    split2(av[j], hi, lo);      fhi[0][j] = hi; flo[0][j] = lo;
    split2(av[8 + j], hi, lo);  fhi[1][j] = hi; flo[1][j] = lo;
    split2(gv[j], hi, lo);      fhi[2][j] = hi; flo[2][j] = lo;
    split2(gv[8 + j], hi, lo);  fhi[3][j] = hi; flo[3][j] = lo;
  }

  floatx4 acc[4];
#pragma unroll
  for (int t = 0; t < 4; ++t) acc[t] = (floatx4){0.f, 0.f, 0.f, 0.f};
#pragma unroll
  for (int t = 0; t < 4; ++t) {
    const short* whi = &w1hi[(t * 16 + m) * PADU + quad * 8];
    const short* wlo = &w1lo[(t * 16 + m) * PADU + quad * 8];
#pragma unroll
    for (int c = 0; c < 4; ++c) {
      acc[t] = MFMA(fhi[c], *(const short8*)(whi + 32 * c), acc[t]);
      acc[t] = MFMA(flo[c], *(const short8*)(whi + 32 * c), acc[t]);
      acc[t] = MFMA(fhi[c], *(const short8*)(wlo + 32 * c), acc[t]);
    }
  }

  float* tbf = tbuf[wave];
#pragma unroll
  for (int t = 0; t < 4; ++t) {
    int col = t * 16 + m;
    float bb = b1s[col];
#pragma unroll
    for (int r = 0; r < 4; ++r)
      tbf[(quad * 4 + r) * PADT + col] = fmaxf(acc[t][r] + bb, 0.f);
  }
  __syncthreads();

  *(floatx4*)(av + 0)  = *(const floatx4*)(&tbf[m * PADT + quad * 8]);
  *(floatx4*)(av + 4)  = *(const floatx4*)(&tbf[m * PADT + quad * 8 + 4]);
  *(floatx4*)(av + 8)  = *(const floatx4*)(&tbf[m * PADT + 32 + quad * 8]);
  *(floatx4*)(av + 12) = *(const floatx4*)(&tbf[m * PADT + 32 + quad * 8 + 4]);
  short8 thi0, tlo0, thi1, tlo1;
#pragma unroll
  for (int j = 0; j < 8; ++j) {
    short hi, lo;
    split2(av[j], hi, lo);     thi0[j] = hi; tlo0[j] = lo;
    split2(av[8 + j], hi, lo); thi1[j] = hi; tlo1[j] = lo;
  }

  floatx4 mac[4];
#pragma unroll
  for (int t = 0; t < 4; ++t) mac[t] = (floatx4){0.f, 0.f, 0.f, 0.f};
#pragma unroll
  for (int t = 0; t < 4; ++t) {
    const short* whi = &w2hi[(t * 16 + m) * PADW + quad * 8];
    const short* wlo = &w2lo[(t * 16 + m) * PADW + quad * 8];
    mac[t] = MFMA(thi0, *(const short8*)(whi), mac[t]);
    mac[t] = MFMA(thi1, *(const short8*)(whi + 32), mac[t]);
    mac[t] = MFMA(tlo0, *(const short8*)(whi), mac[t]);
    mac[t] = MFMA(tlo1, *(const short8*)(whi + 32), mac[t]);
    mac[t] = MFMA(thi0, *(const short8*)(wlo), mac[t]);
    mac[t] = MFMA(thi1, *(const short8*)(wlo + 32), mac[t]);
  }

#pragma unroll
  for (int t = 0; t < 4; ++t) {
    int col = t * 16 + m;
    float bb = b2s[col], ss = scl[col], ff = sft[col];
#pragma unroll
    for (int r = 0; r < 4; ++r) {
      int nrow = nBase + quad * 4 + r;
      if (nrow < N) {
        float hv = (mac[t][r] + bb) * ss + ff;
        float ho = h[(long)nrow * H + col];
        hout[(long)nrow * H + col] = fmaxf(hv + ho, 0.f);
      }
    }
  }
}

__global__ __launch_bounds__(256) void k_out(
    const float* __restrict__ h, const void* __restrict__ W1, const void* __restrict__ B1,
    const void* __restrict__ W2, const void* __restrict__ B2,
    void* __restrict__ out, const int* __restrict__ flag, int NQ) {
  __shared__ float w1s[64 * 32];
  __shared__ float b1sh[32], w2s[32];
  bool isf32 = (*flag != 0);
  int tid = threadIdx.x;
  for (int idx = tid; idx < 2048; idx += 256) w1s[idx] = ldf(W1, idx, isf32);
  if (tid < 32) { b1sh[tid] = ldf(B1, tid, isf32); w2s[tid] = ldf(W2, tid, isf32); }
  __syncthreads();
  int v = blockIdx.x * 256 + tid;
  if (v >= NQ) return;
  float hr[64];
  const float* hp = h + (long)v * H;
#pragma unroll
  for (int j = 0; j < 64; ++j) hr[j] = hp[j];
  float accum = ldf(B2, 0, isf32);
#pragma unroll 4
  for (int k = 0; k < 32; ++k) {
    float t = b1sh[k];
#pragma unroll
    for (int j = 0; j < 64; ++j) t += hr[j] * w1s[j * 32 + k];
    accum += fmaxf(t, 0.f) * w2s[k];
  }
  if (isf32) ((float*)out)[v] = accum;
  else ((short*)out)[v] = f2bf(accum);
}

extern "C" void kernel_launch(void* const* d_in, const int* in_sizes, int n_in,
                              void* d_out, int out_size, void* d_ws, size_t ws_size,
                              hipStream_t stream) {
  const void* x      = d_in[0];
  const int*  ei     = (const int*)d_in[1];
  const void* w_in   = d_in[3];
  const void* b_in   = d_in[4];
  const void* msg_w1 = d_in[5];
  const void* msg_b1 = d_in[6];
  const void* msg_w2 = d_in[7];
  const void* msg_b2 = d_in[8];
  const void* upd_w1 = d_in[9];
  const void* upd_b1 = d_in[10];
  const void* upd_w2 = d_in[11];
  const void* upd_b2 = d_in[12];
  const void* bn_g   = d_in[13];
  const void* bn_b   = d_in[14];
  const void* bn_m   = d_in[15];
  const void* bn_v   = d_in[16];
  const void* out_w1 = d_in[17];
  const void* out_b1 = d_in[18];
  const void* out_w2 = d_in[19];
  const void* out_b2 = d_in[20];

  const int N = in_sizes[0] / 3;
  const int E = in_sizes[1] / 2;
  const int L = in_sizes[5] / (H * H);
  const int* srcI = ei;
  const int* dstI = ei + E;

  // workspace layout (256B-aligned slots); flag slot also holds work-steal ctrs
  size_t off = 0;
  auto alloc = [&](size_t bytes) { size_t o = off; off += (bytes + 255) & ~(size_t)255; return o; };
  size_t o_flag   = alloc(256);
  size_t o_hhi    = alloc((size_t)N * H * sizeof(short));
  size_t o_hlo    = alloc((size_t)N * H * sizeof(short));
  size_t o_agg    = alloc((size_t)N * H * sizeof(unsigned int));
  size_t o_rowptr = alloc((size_t)(N + 1) * sizeof(int));
  size_t o_cursor = alloc((size_t)N * sizeof(int));
  size_t o_bsum   = alloc(256 * sizeof(int));
  size_t o_bexcl  = alloc(256 * sizeof(int));
  size_t o_srcS   = alloc((size_t)E * sizeof(int));
  const size_t needNew = off;
  const int NB = (N + 1023) >> 10;
  const bool newPath = (ws_size >= needNew) && (NB <= 256) && (2 * L + 1 <= 64);

  char* ws = (char*)d_ws;
  int*   flag   = (int*)(ws + o_flag);
  int*   ctrs   = flag + 1;  // ctrs[i]: msg layer i; ctrs[L+i]: upd layer i
  short* hhi    = (short*)(ws + o_hhi);
  short* hlo    = (short*)(ws + o_hlo);
  unsigned int* agg = (unsigned int*)(ws + o_agg);
  int*   rowptr = (int*)(ws + o_rowptr);
  int*   deg    = (int*)(ws + o_cursor);
  int*   bsum   = (int*)(ws + o_bsum);
  int*   bexcl  = (int*)(ws + o_bexcl);
  int*   srcS   = (int*)(ws + o_srcS);

  hipMemsetAsync(flag, 0, 256, stream);  // zeroes flag + all ctrs; probe rewrites flag
  k_probe<<<1, 256, 0, stream>>>((const short*)x, flag);

  if (newPath) {
    k_input2<<<(N * H + 255) / 256, 256, 0, stream>>>(x, w_in, b_in, hhi, hlo, flag, N);

    hipMemsetAsync(deg, 0, (size_t)N * sizeof(int), stream);
    k_hist<<<(E + 255) / 256, 256, 0, stream>>>(dstI, deg, E);
    k_scan_local<<<NB, 256, 0, stream>>>(deg, rowptr, bsum, N);
    k_scan_block<<<1, 256, 0, stream>>>(bsum, bexcl, NB);
    k_scan_add<<<(N + 256) / 256, 256, 0, stream>>>(rowptr, deg, bexcl, N, E);
    k_scatter<<<(E + 255) / 256, 256, 0, stream>>>(srcI, dstI, deg, srcS, E);

    const int MSG_BLOCKS = 1024;  // 34.4KB LDS -> 4 blocks/CU, all co-resident
    const int UPD_BLOCKS = 512;   // 66.4KB LDS -> 2 blocks/CU
    for (int i = 0; i < L; ++i) {
      long oW = (long)i * H * H, oU = (long)i * 2 * H * H, oB = (long)i * H;
      k_msg2<<<MSG_BLOCKS, 256, 0, stream>>>(hhi, rowptr, srcS,
          msg_w1, msg_b1, msg_w2, msg_b2, oW, oB, agg, flag, N, ctrs + i);
      k_upd3<<<UPD_BLOCKS, 256, 0, stream>>>(hhi, hlo, agg,
          upd_w1, upd_b1, upd_w2, upd_b2, bn_g, bn_b, bn_m, bn_v,
          oU, oW, oB, flag, N, ctrs + L + i);
    }
    k_out2<<<(out_size + 255) / 256, 256, 0, stream>>>(hhi, hlo,
        out_w1, out_b1, out_w2, out_b2, d_out, flag, out_size);
  } else {
    // fallback: round-3 atomic path with f32 h
    const size_t hBytes   = (size_t)N * H * sizeof(float);
    const size_t aggF32B  = (size_t)N * H * sizeof(float);
    const size_t aggBf16B = (size_t)N * H * sizeof(short);
    float* hA2 = (float*)(ws + 256);
    void* agg2 = (void*)((char*)hA2 + hBytes);
    const bool af32 = (ws_size >= 256 + hBytes + aggF32B);
    const size_t aggBytes = af32 ? aggF32B : aggBf16B;
    k_input<<<(N * H + 255) / 256, 256, 0, stream>>>(x, w_in, b_in, hA2, flag, N);
    for (int i = 0; i < L; ++i) {
      long oW = (long)i * H * H, oU = (long)i * 2 * H * H, oB = (long)i * H;
      hipMemsetAsync(agg2, 0, aggBytes, stream);
      if (af32) {
        k_msg<true><<<(E + 63) / 64, 256, 0, stream>>>(hA2, srcI, dstI,
            msg_w1, msg_b1, msg_w2, msg_b2, oW, oB, agg2, flag, E);
        k_upd<true><<<(N + 63) / 64, 256, 0, stream>>>(hA2, agg2,
            upd_w1, upd_b1, upd_w2, upd_b2, bn_g, bn_b, bn_m, bn_v,
            oU, oW, oB, hA2, flag, N);
      } else {
        k_msg<false><<<(E + 63) / 64, 256, 0, stream>>>(hA2, srcI, dstI,
            msg_w1, msg_b1, msg_w2, msg_b2, oW, oB, agg2, flag, E);
        k_upd<false><<<(N + 63) / 64, 256, 0, stream>>>(hA2, agg2,
            upd_w1, upd_b1, upd_w2, upd_b2, bn_g, bn_b, bn_m, bn_v,
            oU, oW, oB, hA2, flag, N);
      }
    }
    k_out<<<(out_size + 255) / 256, 256, 0, stream>>>(hA2,
        out_w1, out_b1, out_w2, out_b2, d_out, flag, out_size);
  }
}

// Round 7
// 1449.967 us; speedup vs baseline: 1.2245x; 1.2245x over previous
//
#include <hip/hip_runtime.h>
#include <hip/hip_bf16.h>

#define H 64
#define PADW 88    // old-path bf16 plane stride (shorts)
#define PADU 136   // old-path bf16 plane stride K=128 (shorts)
#define PADT 68    // f32 transpose-buffer stride (floats)
#define BSTR 68    // batch-buffer row stride (dwords)

typedef __attribute__((ext_vector_type(8))) short short8;
typedef __attribute__((ext_vector_type(4))) float floatx4;
typedef __attribute__((ext_vector_type(4))) unsigned int uintx4;

#define MFMA(a, b, c) __builtin_amdgcn_mfma_f32_16x16x32_bf16(a, b, c, 0, 0, 0)

__device__ __forceinline__ float bf2f(short s) {
  union { unsigned int u; float f; } v;
  v.u = ((unsigned int)(unsigned short)s) << 16;
  return v.f;
}
__device__ __forceinline__ short f2bf(float f) {
  union { float f; unsigned int u; } v; v.f = f;
  unsigned int r = v.u + 0x7fffu + ((v.u >> 16) & 1u);  // RNE
  return (short)(r >> 16);
}
__device__ __forceinline__ void split2(float v, short& hi, short& lo) {
  hi = f2bf(v);
  lo = f2bf(v - bf2f(hi));
}
__device__ __forceinline__ unsigned int packhl(float v) {
  short hi, lo; split2(v, hi, lo);
  return ((unsigned int)(unsigned short)hi << 16) | (unsigned int)(unsigned short)lo;
}
__device__ __forceinline__ float ldf(const void* p, long idx, bool isf32) {
  return isf32 ? ((const float*)p)[idx] : bf2f(((const short*)p)[idx]);
}
__device__ __forceinline__ void unpack8(const unsigned int* p, short8& hi, short8& lo) {
  unsigned int u[8];
  *(uintx4*)(u) = *(const uintx4*)(p);
  *(uintx4*)(u + 4) = *(const uintx4*)(p + 4);
#pragma unroll
  for (int j = 0; j < 8; ++j) { hi[j] = (short)(u[j] >> 16); lo[j] = (short)(u[j] & 0xffff); }
}

// dtype probe
__global__ void k_probe(const short* __restrict__ x, int* __restrict__ flag) {
  __shared__ int cnt;
  if (threadIdx.x == 0) cnt = 0;
  __syncthreads();
  short s = x[threadIdx.x];
  int e = (s >> 7) & 0xFF;
  int insane = (e != 0 && (e < 100 || e > 140)) ? 1 : 0;
  atomicAdd(&cnt, insane);
  __syncthreads();
  if (threadIdx.x == 0) *flag = (cnt > 64) ? 1 : 0;  // 1 = f32 inputs
}

// h0 = relu(x @ w_in + b_in) -> hi/lo planes
__global__ void k_input2(const void* __restrict__ x, const void* __restrict__ w,
                         const void* __restrict__ b, short* __restrict__ hhi,
                         short* __restrict__ hlo, const int* __restrict__ flag, int N) {
  bool isf32 = (*flag != 0);
  int idx = blockIdx.x * 256 + threadIdx.x;
  if (idx >= N * H) return;
  int v = idx >> 6, k = idx & 63;
  float acc = ldf(b, k, isf32);
#pragma unroll
  for (int d = 0; d < 3; ++d)
    acc += ldf(x, (long)v * 3 + d, isf32) * ldf(w, d * 64 + k, isf32);
  float r = fmaxf(acc, 0.f);
  short hi, lo; split2(r, hi, lo);
  hhi[idx] = hi; hlo[idx] = lo;
}

// ---------------- CSR build (counting sort by dst) ----------------

__global__ void k_hist(const int* __restrict__ dstI, int* __restrict__ deg, int E) {
  int e = blockIdx.x * 256 + threadIdx.x;
  if (e < E) atomicAdd(&deg[dstI[e]], 1);
}

__global__ void k_scan_local(const int* __restrict__ deg, int* __restrict__ rowptr,
                             int* __restrict__ bsum, int N) {
  __shared__ int s[256];
  int tid = threadIdx.x;
  int base = blockIdx.x * 1024 + tid * 4;
  int v0 = (base + 0 < N) ? deg[base + 0] : 0;
  int v1 = (base + 1 < N) ? deg[base + 1] : 0;
  int v2 = (base + 2 < N) ? deg[base + 2] : 0;
  int v3 = (base + 3 < N) ? deg[base + 3] : 0;
  int tsum = v0 + v1 + v2 + v3;
  s[tid] = tsum;
  __syncthreads();
  for (int off = 1; off < 256; off <<= 1) {
    int x = (tid >= off) ? s[tid - off] : 0;
    __syncthreads();
    s[tid] += x;
    __syncthreads();
  }
  int excl = s[tid] - tsum;
  if (base + 0 < N) rowptr[base + 0] = excl;
  if (base + 1 < N) rowptr[base + 1] = excl + v0;
  if (base + 2 < N) rowptr[base + 2] = excl + v0 + v1;
  if (base + 3 < N) rowptr[base + 3] = excl + v0 + v1 + v2;
  if (tid == 255) bsum[blockIdx.x] = s[255];
}

__global__ void k_scan_block(const int* __restrict__ bsum, int* __restrict__ bexcl, int nb) {
  __shared__ int s[256];
  int tid = threadIdx.x;
  int v = (tid < nb) ? bsum[tid] : 0;
  s[tid] = v;
  __syncthreads();
  for (int off = 1; off < 256; off <<= 1) {
    int x = (tid >= off) ? s[tid - off] : 0;
    __syncthreads();
    s[tid] += x;
    __syncthreads();
  }
  bexcl[tid] = s[tid] - v;
}

__global__ void k_scan_add(int* __restrict__ rowptr, int* __restrict__ cursor,
                           const int* __restrict__ bexcl, int N, int E) {
  int i = blockIdx.x * 256 + threadIdx.x;
  if (i < N) {
    int v = rowptr[i] + bexcl[i >> 10];
    rowptr[i] = v;
    cursor[i] = v;
  }
  if (i == N) rowptr[N] = E;
}

__global__ void k_scatter(const int* __restrict__ srcI, const int* __restrict__ dstI,
                          int* __restrict__ cursor, int* __restrict__ srcS, int E) {
  int e = blockIdx.x * 256 + threadIdx.x;
  if (e >= E) return;
  int d = dstI[e];
  int p = atomicAdd(&cursor[d], 1);
  srcS[p] = srcI[e];
}

// ---------------- persistent message kernel v4 ----------------
// Work-stealing over 16-node batches. Per batch: rowptr[17] preloaded into lanes;
// nodes processed in PAIRS with interleaved srcS/gather streams (2x memory-level
// parallelism per wave). GEMM1 hi-only (8 MFMA/chunk, W1 in regs). GEMM2 once per
// batch (linearity of W2; bias as deg*b2). agg written f32.
__global__ __launch_bounds__(256) void k_msg2(
    const short* __restrict__ hhi,
    const int* __restrict__ rowptr, const int* __restrict__ srcS,
    const void* __restrict__ W1, const void* __restrict__ B1,
    const void* __restrict__ W2, const void* __restrict__ B2,
    long oW, long oB, float* __restrict__ agg, const int* __restrict__ flag,
    int N, int* __restrict__ ctr) {
  __shared__ unsigned int wbuf[4096];          // staged W1 -> regs, then restaged W2
  __shared__ unsigned int batch[4][16 * BSTR]; // per-wave sumP rows (packed hi|lo)
  __shared__ int degs[4][16];
  __shared__ float b1s[64], b2s[64];

  bool isf32 = (*flag != 0);
  int tid = threadIdx.x;
  for (int idx = tid; idx < 4096; idx += 256) {
    int k = idx >> 6, n = idx & 63;  // W[k=in][n=out] row-major
    int t = n >> 4, m2 = n & 15, c = k >> 5, q2 = (k >> 3) & 3, j = k & 7;
    wbuf[(((t * 2 + c) * 64) + (q2 * 16 + m2)) * 8 + j] = packhl(ldf(W1, oW + idx, isf32));
  }
  if (tid < 64) { b1s[tid] = ldf(B1, oB + tid, isf32); b2s[tid] = ldf(B2, oB + tid, isf32); }
  __syncthreads();

  const int wave = tid >> 6, lane = tid & 63;
  const int m = lane & 15, q = lane >> 4;

  // hoist W1 (hi only) fragments into registers
  short8 w1hiR[4][2];
#pragma unroll
  for (int t = 0; t < 4; ++t)
#pragma unroll
    for (int c = 0; c < 2; ++c) {
      short8 hi, lo;
      unpack8(&wbuf[(((t * 2 + c) * 64) + lane) * 8], hi, lo);
      w1hiR[t][c] = hi;
    }
  float b1r[4];
#pragma unroll
  for (int t = 0; t < 4; ++t) b1r[t] = b1s[16 * t + m];
  __syncthreads();
  // restage W2 into the same buffer
  for (int idx = tid; idx < 4096; idx += 256) {
    int k = idx >> 6, n = idx & 63;
    int t = n >> 4, m2 = n & 15, c = k >> 5, q2 = (k >> 3) & 3, j = k & 7;
    wbuf[(((t * 2 + c) * 64) + (q2 * 16 + m2)) * 8 + j] = packhl(ldf(W2, oW + idx, isf32));
  }
  __syncthreads();

  const int nBatch = (N + 15) >> 4;
  unsigned int* bb_buf = batch[wave];

  for (;;) {
    int bb;
    if (lane == 0) bb = atomicAdd(ctr, 1);
    bb = __shfl(bb, 0);
    if (bb >= nBatch) break;
    const int nb0 = bb * 16;

    // preload rowptr[nb0 .. nb0+16] (one coalesced load; off the per-node chain)
    int rpv = 0;
    if (lane < 17) {
      int idx = nb0 + lane;
      rpv = rowptr[idx <= N ? idx : N];  // nodes >= N collapse to deg 0
    }

    for (int i = 0; i < 8; ++i) {
      const int bA = 2 * i, bB = 2 * i + 1;
      const int rsA = __shfl(rpv, bA);
      const int reA = __shfl(rpv, bA + 1);
      const int rsB = reA;  // CSR contiguity
      const int reB = __shfl(rpv, bB + 1);

      floatx4 sumA[4], sumB[4];
#pragma unroll
      for (int t = 0; t < 4; ++t) {
        sumA[t] = (floatx4){0.f, 0.f, 0.f, 0.f};
        sumB[t] = (floatx4){0.f, 0.f, 0.f, 0.f};
      }

      int baseA = rsA, baseB = rsB;
      while ((baseA < reA) || (baseB < reB)) {
        const bool doA = baseA < reA, doB = baseB < reB;
        int svA = 0, svB = 0;
        if (doA) { int e = baseA + m; svA = srcS[e < reA ? e : reA - 1]; }
        if (doB) { int e = baseB + m; svB = srcS[e < reB ? e : reB - 1]; }
        short8 hA0, hA1, hB0, hB1;
        if (doA) {
          const short* p = hhi + (long)svA * H;
          hA0 = *(const short8*)(p + 8 * q);
          hA1 = *(const short8*)(p + 32 + 8 * q);
        }
        if (doB) {
          const short* p = hhi + (long)svB * H;
          hB0 = *(const short8*)(p + 8 * q);
          hB1 = *(const short8*)(p + 32 + 8 * q);
        }
        if (doA) {
          floatx4 p4[4];
#pragma unroll
          for (int t = 0; t < 4; ++t) p4[t] = (floatx4){0.f, 0.f, 0.f, 0.f};
#pragma unroll
          for (int t = 0; t < 4; ++t) {
            p4[t] = MFMA(hA0, w1hiR[t][0], p4[t]);
            p4[t] = MFMA(hA1, w1hiR[t][1], p4[t]);
          }
#pragma unroll
          for (int r = 0; r < 4; ++r) {
            bool ok = (baseA + 4 * q + r) < reA;
#pragma unroll
            for (int t = 0; t < 4; ++t) {
              float v = fmaxf(p4[t][r] + b1r[t], 0.f);
              sumA[t][r] += ok ? v : 0.f;
            }
          }
          baseA += 16;
        }
        if (doB) {
          floatx4 p4[4];
#pragma unroll
          for (int t = 0; t < 4; ++t) p4[t] = (floatx4){0.f, 0.f, 0.f, 0.f};
#pragma unroll
          for (int t = 0; t < 4; ++t) {
            p4[t] = MFMA(hB0, w1hiR[t][0], p4[t]);
            p4[t] = MFMA(hB1, w1hiR[t][1], p4[t]);
          }
#pragma unroll
          for (int r = 0; r < 4; ++r) {
            bool ok = (baseB + 4 * q + r) < reB;
#pragma unroll
            for (int t = 0; t < 4; ++t) {
              float v = fmaxf(p4[t][r] + b1r[t], 0.f);
              sumB[t][r] += ok ? v : 0.f;
            }
          }
          baseB += 16;
        }
      }

      float sfA[4], sfB[4];
#pragma unroll
      for (int t = 0; t < 4; ++t) {
        float sA = sumA[t][0] + sumA[t][1] + sumA[t][2] + sumA[t][3];
        sA += __shfl_xor(sA, 16);
        sA += __shfl_xor(sA, 32);
        sfA[t] = sA;
        float sB = sumB[t][0] + sumB[t][1] + sumB[t][2] + sumB[t][3];
        sB += __shfl_xor(sB, 16);
        sB += __shfl_xor(sB, 32);
        sfB[t] = sB;
      }
      float selA = (q == 0) ? sfA[0] : (q == 1) ? sfA[1] : (q == 2) ? sfA[2] : sfA[3];
      float selB = (q == 0) ? sfB[0] : (q == 1) ? sfB[1] : (q == 2) ? sfB[2] : sfB[3];
      bb_buf[bA * BSTR + lane] = packhl(selA);
      bb_buf[bB * BSTR + lane] = packhl(selB);
      if (lane == 0) { degs[wave][bA] = reA - rsA; degs[wave][bB] = reB - rsB; }
    }

    // batch GEMM2: sumP(16x64) @ W2 (full hi+lo precision)
    short8 ahi[2], alo[2];
#pragma unroll
    for (int c = 0; c < 2; ++c)
      unpack8(&bb_buf[m * BSTR + 32 * c + 8 * q], ahi[c], alo[c]);

    floatx4 m4[4];
#pragma unroll
    for (int t = 0; t < 4; ++t) m4[t] = (floatx4){0.f, 0.f, 0.f, 0.f};
#pragma unroll
    for (int t = 0; t < 4; ++t) {
      short8 b0h, b0l, b1h, b1l;
      unpack8(&wbuf[(((t * 2 + 0) * 64) + lane) * 8], b0h, b0l);
      unpack8(&wbuf[(((t * 2 + 1) * 64) + lane) * 8], b1h, b1l);
      m4[t] = MFMA(ahi[0], b0h, m4[t]);
      m4[t] = MFMA(ahi[1], b1h, m4[t]);
      m4[t] = MFMA(alo[0], b0h, m4[t]);
      m4[t] = MFMA(alo[1], b1h, m4[t]);
      m4[t] = MFMA(ahi[0], b0l, m4[t]);
      m4[t] = MFMA(ahi[1], b1l, m4[t]);
    }
#pragma unroll
    for (int r = 0; r < 4; ++r) {
      int nd = nb0 + 4 * q + r;
      if (nd < N) {
        float dv = (float)degs[wave][4 * q + r];
#pragma unroll
        for (int t = 0; t < 4; ++t) {
          int col = 16 * t + m;
          agg[(long)nd * H + col] = m4[t][r] + dv * b2s[col];
        }
      }
    }
  }
}

// ---------------- update kernel (round-5 proven version) ----------------
// per-node update MLP + BN + residual relu; h in hi/lo planes, in-place safe.
__global__ __launch_bounds__(256) void k_upd2(
    short* __restrict__ hhi, short* __restrict__ hlo, const float* __restrict__ agg,
    const void* __restrict__ W1, const void* __restrict__ B1,
    const void* __restrict__ W2, const void* __restrict__ B2,
    const void* __restrict__ G, const void* __restrict__ Bb,
    const void* __restrict__ Mm, const void* __restrict__ Vv,
    long oU, long oW, long oB, const int* __restrict__ flag, int N) {
  __shared__ short w1hi[64 * PADU], w1lo[64 * PADU];
  __shared__ short w2hi[64 * PADW], w2lo[64 * PADW];
  __shared__ float b1s[64], b2s[64], scl[64], sft[64];
  __shared__ float tbuf[4][16 * PADT];

  bool isf32 = (*flag != 0);
  int tid = threadIdx.x;
  for (int idx = tid; idx < 8192; idx += 256) {
    int j = idx >> 6, k = idx & 63;
    short hi, lo;
    split2(ldf(W1, oU + idx, isf32), hi, lo);
    w1hi[k * PADU + j] = hi; w1lo[k * PADU + j] = lo;
  }
  for (int idx = tid; idx < 4096; idx += 256) {
    int j = idx >> 6, k = idx & 63;
    short hi, lo;
    split2(ldf(W2, oW + idx, isf32), hi, lo);
    w2hi[k * PADW + j] = hi; w2lo[k * PADW + j] = lo;
  }
  if (tid < 64) {
    b1s[tid] = ldf(B1, oB + tid, isf32);
    b2s[tid] = ldf(B2, oB + tid, isf32);
    float s = ldf(G, oB + tid, isf32) * rsqrtf(ldf(Vv, oB + tid, isf32) + 1e-5f);
    scl[tid] = s;
    sft[tid] = ldf(Bb, oB + tid, isf32) - ldf(Mm, oB + tid, isf32) * s;
  }
  __syncthreads();

  const int wave = tid >> 6, lane = tid & 63;
  const int m = lane & 15, quad = lane >> 4;
  const int nBase = (blockIdx.x * 4 + wave) * 16;
  int node = nBase + m;
  int nc = node < N ? node : N - 1;

  short8 fhi[4], flo[4];
  fhi[0] = *(const short8*)(hhi + (long)nc * H + quad * 8);
  fhi[1] = *(const short8*)(hhi + (long)nc * H + 32 + quad * 8);
  flo[0] = *(const short8*)(hlo + (long)nc * H + quad * 8);
  flo[1] = *(const short8*)(hlo + (long)nc * H + 32 + quad * 8);
  {
    const float* arow = agg + (long)nc * H;
    float gv[16];
    *(floatx4*)(gv + 0)  = *(const floatx4*)(arow + quad * 8);
    *(floatx4*)(gv + 4)  = *(const floatx4*)(arow + quad * 8 + 4);
    *(floatx4*)(gv + 8)  = *(const floatx4*)(arow + 32 + quad * 8);
    *(floatx4*)(gv + 12) = *(const floatx4*)(arow + 32 + quad * 8 + 4);
#pragma unroll
    for (int j = 0; j < 8; ++j) {
      short hi, lo;
      split2(gv[j], hi, lo);      fhi[2][j] = hi; flo[2][j] = lo;
      split2(gv[8 + j], hi, lo);  fhi[3][j] = hi; flo[3][j] = lo;
    }
  }

  floatx4 acc[4];
#pragma unroll
  for (int t = 0; t < 4; ++t) acc[t] = (floatx4){0.f, 0.f, 0.f, 0.f};
#pragma unroll
  for (int t = 0; t < 4; ++t) {
    const short* whi = &w1hi[(t * 16 + m) * PADU + quad * 8];
    const short* wlo = &w1lo[(t * 16 + m) * PADU + quad * 8];
#pragma unroll
    for (int c = 0; c < 4; ++c) {
      acc[t] = MFMA(fhi[c], *(const short8*)(whi + 32 * c), acc[t]);
      acc[t] = MFMA(flo[c], *(const short8*)(whi + 32 * c), acc[t]);
      acc[t] = MFMA(fhi[c], *(const short8*)(wlo + 32 * c), acc[t]);
    }
  }

  float* tb = tbuf[wave];
#pragma unroll
  for (int t = 0; t < 4; ++t) {
    int col = t * 16 + m;
    float bb = b1s[col];
#pragma unroll
    for (int r = 0; r < 4; ++r)
      tb[(quad * 4 + r) * PADT + col] = fmaxf(acc[t][r] + bb, 0.f);
  }
  __syncthreads();

  float av[16];
  *(floatx4*)(av + 0)  = *(const floatx4*)(&tb[m * PADT + quad * 8]);
  *(floatx4*)(av + 4)  = *(const floatx4*)(&tb[m * PADT + quad * 8 + 4]);
  *(floatx4*)(av + 8)  = *(const floatx4*)(&tb[m * PADT + 32 + quad * 8]);
  *(floatx4*)(av + 12) = *(const floatx4*)(&tb[m * PADT + 32 + quad * 8 + 4]);
  short8 thi0, tlo0, thi1, tlo1;
#pragma unroll
  for (int j = 0; j < 8; ++j) {
    short hi, lo;
    split2(av[j], hi, lo);     thi0[j] = hi; tlo0[j] = lo;
    split2(av[8 + j], hi, lo); thi1[j] = hi; tlo1[j] = lo;
  }

  floatx4 mac[4];
#pragma unroll
  for (int t = 0; t < 4; ++t) mac[t] = (floatx4){0.f, 0.f, 0.f, 0.f};
#pragma unroll
  for (int t = 0; t < 4; ++t) {
    const short* whi = &w2hi[(t * 16 + m) * PADW + quad * 8];
    const short* wlo = &w2lo[(t * 16 + m) * PADW + quad * 8];
    mac[t] = MFMA(thi0, *(const short8*)(whi), mac[t]);
    mac[t] = MFMA(thi1, *(const short8*)(whi + 32), mac[t]);
    mac[t] = MFMA(tlo0, *(const short8*)(whi), mac[t]);
    mac[t] = MFMA(tlo1, *(const short8*)(whi + 32), mac[t]);
    mac[t] = MFMA(thi0, *(const short8*)(wlo), mac[t]);
    mac[t] = MFMA(thi1, *(const short8*)(wlo + 32), mac[t]);
  }

#pragma unroll
  for (int t = 0; t < 4; ++t) {
    int col = t * 16 + m;
    float bb = b2s[col], ss = scl[col], ff = sft[col];
#pragma unroll
    for (int r = 0; r < 4; ++r) {
      int nrow = nBase + quad * 4 + r;
      if (nrow < N) {
        long el = (long)nrow * H + col;
        float hv = (mac[t][r] + bb) * ss + ff;
        float ho = bf2f(hhi[el]) + bf2f(hlo[el]);
        float hn = fmaxf(hv + ho, 0.f);
        short hi2, lo2; split2(hn, hi2, lo2);
        hhi[el] = hi2; hlo[el] = lo2;
      }
    }
  }
}

// readout from hi/lo planes
__global__ __launch_bounds__(256) void k_out2(
    const short* __restrict__ hhi, const short* __restrict__ hlo,
    const void* __restrict__ W1, const void* __restrict__ B1,
    const void* __restrict__ W2, const void* __restrict__ B2,
    void* __restrict__ out, const int* __restrict__ flag, int NQ) {
  __shared__ float w1s[64 * 32];
  __shared__ float b1sh[32], w2s[32];
  bool isf32 = (*flag != 0);
  int tid = threadIdx.x;
  for (int idx = tid; idx < 2048; idx += 256) w1s[idx] = ldf(W1, idx, isf32);
  if (tid < 32) { b1sh[tid] = ldf(B1, tid, isf32); w2s[tid] = ldf(W2, tid, isf32); }
  __syncthreads();
  int v = blockIdx.x * 256 + tid;
  if (v >= NQ) return;
  float hr[64];
#pragma unroll
  for (int j = 0; j < 64; ++j)
    hr[j] = bf2f(hhi[(long)v * H + j]) + bf2f(hlo[(long)v * H + j]);
  float accum = ldf(B2, 0, isf32);
#pragma unroll 4
  for (int k = 0; k < 32; ++k) {
    float t = b1sh[k];
#pragma unroll
    for (int j = 0; j < 64; ++j) t += hr[j] * w1s[j * 32 + k];
    accum += fmaxf(t, 0.f) * w2s[k];
  }
  if (isf32) ((float*)out)[v] = accum;
  else ((short*)out)[v] = f2bf(accum);
}

// ---------------- old fallback path (round-3, f32 h) ----------------

__global__ void k_input(const void* __restrict__ x, const void* __restrict__ w,
                        const void* __restrict__ b, float* __restrict__ h,
                        const int* __restrict__ flag, int N) {
  bool isf32 = (*flag != 0);
  int idx = blockIdx.x * 256 + threadIdx.x;
  if (idx >= N * H) return;
  int v = idx >> 6, k = idx & 63;
  float acc = ldf(b, k, isf32);
#pragma unroll
  for (int d = 0; d < 3; ++d)
    acc += ldf(x, (long)v * 3 + d, isf32) * ldf(w, d * 64 + k, isf32);
  h[idx] = fmaxf(acc, 0.f);
}

template <bool AF32>
__global__ __launch_bounds__(256) void k_msg(
    const float* __restrict__ h, const int* __restrict__ srcI, const int* __restrict__ dstI,
    const void* __restrict__ W1, const void* __restrict__ B1,
    const void* __restrict__ W2, const void* __restrict__ B2,
    long oW, long oB,
    void* __restrict__ aggv, const int* __restrict__ flag, int E) {
  __shared__ short w1hi[64 * PADW], w1lo[64 * PADW];
  __shared__ short w2hi[64 * PADW], w2lo[64 * PADW];
  __shared__ float b1s[64], b2s[64];
  __shared__ float tbuf[4][16 * PADT];

  bool isf32 = (*flag != 0);
  int tid = threadIdx.x;
  for (int idx = tid; idx < 4096; idx += 256) {
    int j = idx >> 6, k = idx & 63;
    short hi, lo;
    split2(ldf(W1, oW + idx, isf32), hi, lo);
    w1hi[k * PADW + j] = hi; w1lo[k * PADW + j] = lo;
    split2(ldf(W2, oW + idx, isf32), hi, lo);
    w2hi[k * PADW + j] = hi; w2lo[k * PADW + j] = lo;
  }
  if (tid < 64) {
    b1s[tid] = ldf(B1, oB + tid, isf32);
    b2s[tid] = ldf(B2, oB + tid, isf32);
  }
  __syncthreads();

  const int wave = tid >> 6, lane = tid & 63;
  const int m = lane & 15, quad = lane >> 4;
  const int eBase = (blockIdx.x * 4 + wave) * 16;

  int e = eBase + m;
  int ec = e < E ? e : E - 1;
  int sv = srcI[ec];
  int dv = dstI[ec];

  const float* hrow = h + (long)sv * H;
  float av[16];
  *(floatx4*)(av + 0)  = *(const floatx4*)(hrow + quad * 8);
  *(floatx4*)(av + 4)  = *(const floatx4*)(hrow + quad * 8 + 4);
  *(floatx4*)(av + 8)  = *(const floatx4*)(hrow + 32 + quad * 8);
  *(floatx4*)(av + 12) = *(const floatx4*)(hrow + 32 + quad * 8 + 4);
  short8 ahi0, alo0, ahi1, alo1;
#pragma unroll
  for (int j = 0; j < 8; ++j) {
    short hi, lo;
    split2(av[j], hi, lo);     ahi0[j] = hi; alo0[j] = lo;
    split2(av[8 + j], hi, lo); ahi1[j] = hi; alo1[j] = lo;
  }

  floatx4 acc[4];
#pragma unroll
  for (int t = 0; t < 4; ++t) acc[t] = (floatx4){0.f, 0.f, 0.f, 0.f};
#pragma unroll
  for (int t = 0; t < 4; ++t) {
    const short* whi = &w1hi[(t * 16 + m) * PADW + quad * 8];
    const short* wlo = &w1lo[(t * 16 + m) * PADW + quad * 8];
    acc[t] = MFMA(ahi0, *(const short8*)(whi), acc[t]);
    acc[t] = MFMA(ahi1, *(const short8*)(whi + 32), acc[t]);
    acc[t] = MFMA(alo0, *(const short8*)(whi), acc[t]);
    acc[t] = MFMA(alo1, *(const short8*)(whi + 32), acc[t]);
    acc[t] = MFMA(ahi0, *(const short8*)(wlo), acc[t]);
    acc[t] = MFMA(ahi1, *(const short8*)(wlo + 32), acc[t]);
  }

  float* tbf = tbuf[wave];
#pragma unroll
  for (int t = 0; t < 4; ++t) {
    int col = t * 16 + m;
    float bb = b1s[col];
#pragma unroll
    for (int r = 0; r < 4; ++r)
      tbf[(quad * 4 + r) * PADT + col] = fmaxf(acc[t][r] + bb, 0.f);
  }
  __syncthreads();

  *(floatx4*)(av + 0)  = *(const floatx4*)(&tbf[m * PADT + quad * 8]);
  *(floatx4*)(av + 4)  = *(const floatx4*)(&tbf[m * PADT + quad * 8 + 4]);
  *(floatx4*)(av + 8)  = *(const floatx4*)(&tbf[m * PADT + 32 + quad * 8]);
  *(floatx4*)(av + 12) = *(const floatx4*)(&tbf[m * PADT + 32 + quad * 8 + 4]);
#pragma unroll
  for (int j = 0; j < 8; ++j) {
    short hi, lo;
    split2(av[j], hi, lo);     ahi0[j] = hi; alo0[j] = lo;
    split2(av[8 + j], hi, lo); ahi1[j] = hi; alo1[j] = lo;
  }

  floatx4 mac[4];
#pragma unroll
  for (int t = 0; t < 4; ++t) mac[t] = (floatx4){0.f, 0.f, 0.f, 0.f};
#pragma unroll
  for (int t = 0; t < 4; ++t) {
    const short* whi = &w2hi[(t * 16 + m) * PADW + quad * 8];
    const short* wlo = &w2lo[(t * 16 + m) * PADW + quad * 8];
    mac[t] = MFMA(ahi0, *(const short8*)(whi), mac[t]);
    mac[t] = MFMA(ahi1, *(const short8*)(whi + 32), mac[t]);
    mac[t] = MFMA(alo0, *(const short8*)(whi), mac[t]);
    mac[t] = MFMA(alo1, *(const short8*)(whi + 32), mac[t]);
    mac[t] = MFMA(ahi0, *(const short8*)(wlo), mac[t]);
    mac[t] = MFMA(ahi1, *(const short8*)(wlo + 32), mac[t]);
  }

  float* aggF = (float*)aggv;
  short* aggS = (short*)aggv;
#pragma unroll
  for (int t = 0; t < 4; ++t) {
    int col = t * 16 + m;
    float bb = b2s[col];
#pragma unroll
    for (int r = 0; r < 4; ++r) {
      int row = quad * 4 + r;
      int er = eBase + row;
      int dr = __shfl(dv, row);
      float v = mac[t][r] + bb;
      if (AF32) {
        if (er < E) atomicAdd(&aggF[(long)dr * H + col], v);
      } else {
        float v2 = __shfl_down(v, 1);
        if (((m & 1) == 0) && er < E) {
          unsigned int pk = ((unsigned int)(unsigned short)f2bf(v2) << 16) |
                            (unsigned int)(unsigned short)f2bf(v);
          unsafeAtomicAdd((__hip_bfloat162*)&aggS[(long)dr * H + col],
                          *(__hip_bfloat162*)&pk);
        }
      }
    }
  }
}

template <bool AF32>
__global__ __launch_bounds__(256) void k_upd(
    const float* __restrict__ h, const void* __restrict__ aggv,
    const void* __restrict__ W1, const void* __restrict__ B1,
    const void* __restrict__ W2, const void* __restrict__ B2,
    const void* __restrict__ G, const void* __restrict__ Bb,
    const void* __restrict__ Mm, const void* __restrict__ Vv,
    long oU, long oW, long oB,
    float* __restrict__ hout, const int* __restrict__ flag, int N) {
  __shared__ short w1hi[64 * PADU], w1lo[64 * PADU];
  __shared__ short w2hi[64 * PADW], w2lo[64 * PADW];
  __shared__ float b1s[64], b2s[64], scl[64], sft[64];
  __shared__ float tbuf[4][16 * PADT];

  bool isf32 = (*flag != 0);
  int tid = threadIdx.x;
  for (int idx = tid; idx < 8192; idx += 256) {
    int j = idx >> 6, k = idx & 63;
    short hi, lo;
    split2(ldf(W1, oU + idx, isf32), hi, lo);
    w1hi[k * PADU + j] = hi; w1lo[k * PADU + j] = lo;
  }
  for (int idx = tid; idx < 4096; idx += 256) {
    int j = idx >> 6, k = idx & 63;
    short hi, lo;
    split2(ldf(W2, oW + idx, isf32), hi, lo);
    w2hi[k * PADW + j] = hi; w2lo[k * PADW + j] = lo;
  }
  if (tid < 64) {
    b1s[tid] = ldf(B1, oB + tid, isf32);
    b2s[tid] = ldf(B2, oB + tid, isf32);
    float s = ldf(G, oB + tid, isf32) * rsqrtf(ldf(Vv, oB + tid, isf32) + 1e-5f);
    scl[tid] = s;
    sft[tid] = ldf(Bb, oB + tid, isf32) - ldf(Mm, oB + tid, isf32) * s;
  }
  __syncthreads();

  const int wave = tid >> 6, lane = tid & 63;
  const int m = lane & 15, quad = lane >> 4;
  const int nBase = (blockIdx.x * 4 + wave) * 16;
  int node = nBase + m;
  int nc = node < N ? node : N - 1;

  float av[16];
  const float* hrow = h + (long)nc * H;
  *(floatx4*)(av + 0)  = *(const floatx4*)(hrow + quad * 8);
  *(floatx4*)(av + 4)  = *(const floatx4*)(hrow + quad * 8 + 4);
  *(floatx4*)(av + 8)  = *(const floatx4*)(hrow + 32 + quad * 8);
  *(floatx4*)(av + 12) = *(const floatx4*)(hrow + 32 + quad * 8 + 4);
  float gv[16];
  if (AF32) {
    const float* arow = (const float*)aggv + (long)nc * H;
    *(floatx4*)(gv + 0)  = *(const floatx4*)(arow + quad * 8);
    *(floatx4*)(gv + 4)  = *(const floatx4*)(arow + quad * 8 + 4);
    *(floatx4*)(gv + 8)  = *(const floatx4*)(arow + 32 + quad * 8);
    *(floatx4*)(gv + 12) = *(const floatx4*)(arow + 32 + quad * 8 + 4);
  } else {
    const short* arow = (const short*)aggv + (long)nc * H;
#pragma unroll
    for (int j = 0; j < 8; ++j) {
      gv[j] = bf2f(arow[quad * 8 + j]);
      gv[8 + j] = bf2f(arow[32 + quad * 8 + j]);
    }
  }
  short8 fhi[4], flo[4];
#pragma unroll
  for (int j = 0; j < 8; ++j) {
    short hi, lo;
    split2(av[j], hi, lo);      fhi[0][j] = hi; flo[0][j] = lo;
    split2(av[8 + j], hi, lo);  fhi[1][j] = hi; flo[1][j] = lo;
    split2(gv[j], hi, lo);      fhi[2][j] = hi; flo[2][j] = lo;
    split2(gv[8 + j], hi, lo);  fhi[3][j] = hi; flo[3][j] = lo;
  }

  floatx4 acc[4];
#pragma unroll
  for (int t = 0; t < 4; ++t) acc[t] = (floatx4){0.f, 0.f, 0.f, 0.f};
#pragma unroll
  for (int t = 0; t < 4; ++t) {
    const short* whi = &w1hi[(t * 16 + m) * PADU + quad * 8];
    const short* wlo = &w1lo[(t * 16 + m) * PADU + quad * 8];
#pragma unroll
    for (int c = 0; c < 4; ++c) {
      acc[t] = MFMA(fhi[c], *(const short8*)(whi + 32 * c), acc[t]);
      acc[t] = MFMA(flo[c], *(const short8*)(whi + 32 * c), acc[t]);
      acc[t] = MFMA(fhi[c], *(const short8*)(wlo + 32 * c), acc[t]);
    }
  }

  float* tbf = tbuf[wave];
#pragma unroll
  for (int t = 0; t < 4; ++t) {
    int col = t * 16 + m;
    float bb = b1s[col];
#pragma unroll
    for (int r = 0; r < 4; ++r)
      tbf[(quad * 4 + r) * PADT + col] = fmaxf(acc[t][r] + bb, 0.f);
  }
  __syncthreads();

  *(floatx4*)(av + 0)  = *(const floatx4*)(&tbf[m * PADT + quad * 8]);
  *(floatx4*)(av + 4)  = *(const floatx4*)(&tbf[m * PADT + quad * 8 + 4]);
  *(floatx4*)(av + 8)  = *(const floatx4*)(&tbf[m * PADT + 32 + quad * 8]);
  *(floatx4*)(av + 12) = *(const floatx4*)(&tbf[m * PADT + 32 + quad * 8 + 4]);
  short8 thi0, tlo0, thi1, tlo1;
#pragma unroll
  for (int j = 0; j < 8; ++j) {
    short hi, lo;
    split2(av[j], hi, lo);     thi0[j] = hi; tlo0[j] = lo;
    split2(av[8 + j], hi, lo); thi1[j] = hi; tlo1[j] = lo;
  }

  floatx4 mac[4];
#pragma unroll
  for (int t = 0; t < 4; ++t) mac[t] = (floatx4){0.f, 0.f, 0.f, 0.f};
#pragma unroll
  for (int t = 0; t < 4; ++t) {
    const short* whi = &w2hi[(t * 16 + m) * PADW + quad * 8];
    const short* wlo = &w2lo[(t * 16 + m) * PADW + quad * 8];
    mac[t] = MFMA(thi0, *(const short8*)(whi), mac[t]);
    mac[t] = MFMA(thi1, *(const short8*)(whi + 32), mac[t]);
    mac[t] = MFMA(tlo0, *(const short8*)(whi), mac[t]);
    mac[t] = MFMA(tlo1, *(const short8*)(whi + 32), mac[t]);
    mac[t] = MFMA(thi0, *(const short8*)(wlo), mac[t]);
    mac[t] = MFMA(thi1, *(const short8*)(wlo + 32), mac[t]);
  }

#pragma unroll
  for (int t = 0; t < 4; ++t) {
    int col = t * 16 + m;
    float bb = b2s[col], ss = scl[col], ff = sft[col];
#pragma unroll
    for (int r = 0; r < 4; ++r) {
      int nrow = nBase + quad * 4 + r;
      if (nrow < N) {
        float hv = (mac[t][r] + bb) * ss + ff;
        float ho = h[(long)nrow * H + col];
        hout[(long)nrow * H + col] = fmaxf(hv + ho, 0.f);
      }
    }
  }
}

__global__ __launch_bounds__(256) void k_out(
    const float* __restrict__ h, const void* __restrict__ W1, const void* __restrict__ B1,
    const void* __restrict__ W2, const void* __restrict__ B2,
    void* __restrict__ out, const int* __restrict__ flag, int NQ) {
  __shared__ float w1s[64 * 32];
  __shared__ float b1sh[32], w2s[32];
  bool isf32 = (*flag != 0);
  int tid = threadIdx.x;
  for (int idx = tid; idx < 2048; idx += 256) w1s[idx] = ldf(W1, idx, isf32);
  if (tid < 32) { b1sh[tid] = ldf(B1, tid, isf32); w2s[tid] = ldf(W2, tid, isf32); }
  __syncthreads();
  int v = blockIdx.x * 256 + tid;
  if (v >= NQ) return;
  float hr[64];
  const float* hp = h + (long)v * H;
#pragma unroll
  for (int j = 0; j < 64; ++j) hr[j] = hp[j];
  float accum = ldf(B2, 0, isf32);
#pragma unroll 4
  for (int k = 0; k < 32; ++k) {
    float t = b1sh[k];
#pragma unroll
    for (int j = 0; j < 64; ++j) t += hr[j] * w1s[j * 32 + k];
    accum += fmaxf(t, 0.f) * w2s[k];
  }
  if (isf32) ((float*)out)[v] = accum;
  else ((short*)out)[v] = f2bf(accum);
}

extern "C" void kernel_launch(void* const* d_in, const int* in_sizes, int n_in,
                              void* d_out, int out_size, void* d_ws, size_t ws_size,
                              hipStream_t stream) {
  const void* x      = d_in[0];
  const int*  ei     = (const int*)d_in[1];
  const void* w_in   = d_in[3];
  const void* b_in   = d_in[4];
  const void* msg_w1 = d_in[5];
  const void* msg_b1 = d_in[6];
  const void* msg_w2 = d_in[7];
  const void* msg_b2 = d_in[8];
  const void* upd_w1 = d_in[9];
  const void* upd_b1 = d_in[10];
  const void* upd_w2 = d_in[11];
  const void* upd_b2 = d_in[12];
  const void* bn_g   = d_in[13];
  const void* bn_b   = d_in[14];
  const void* bn_m   = d_in[15];
  const void* bn_v   = d_in[16];
  const void* out_w1 = d_in[17];
  const void* out_b1 = d_in[18];
  const void* out_w2 = d_in[19];
  const void* out_b2 = d_in[20];

  const int N = in_sizes[0] / 3;
  const int E = in_sizes[1] / 2;
  const int L = in_sizes[5] / (H * H);
  const int* srcI = ei;
  const int* dstI = ei + E;

  // workspace layout (256B-aligned slots); flag slot also holds work-steal ctrs
  size_t off = 0;
  auto alloc = [&](size_t bytes) { size_t o = off; off += (bytes + 255) & ~(size_t)255; return o; };
  size_t o_flag   = alloc(256);
  size_t o_hhi    = alloc((size_t)N * H * sizeof(short));
  size_t o_hlo    = alloc((size_t)N * H * sizeof(short));
  size_t o_agg    = alloc((size_t)N * H * sizeof(float));
  size_t o_rowptr = alloc((size_t)(N + 1) * sizeof(int));
  size_t o_cursor = alloc((size_t)N * sizeof(int));
  size_t o_bsum   = alloc(256 * sizeof(int));
  size_t o_bexcl  = alloc(256 * sizeof(int));
  size_t o_srcS   = alloc((size_t)E * sizeof(int));
  const size_t needNew = off;
  const int NB = (N + 1023) >> 10;
  const bool newPath = (ws_size >= needNew) && (NB <= 256) && (L + 1 <= 64);

  char* ws = (char*)d_ws;
  int*   flag   = (int*)(ws + o_flag);
  int*   ctrs   = flag + 1;  // ctrs[i]: msg layer i work-steal counter
  short* hhi    = (short*)(ws + o_hhi);
  short* hlo    = (short*)(ws + o_hlo);
  float* agg    = (float*)(ws + o_agg);
  int*   rowptr = (int*)(ws + o_rowptr);
  int*   deg    = (int*)(ws + o_cursor);
  int*   bsum   = (int*)(ws + o_bsum);
  int*   bexcl  = (int*)(ws + o_bexcl);
  int*   srcS   = (int*)(ws + o_srcS);

  hipMemsetAsync(flag, 0, 256, stream);  // zeroes flag + ctrs; probe rewrites flag
  k_probe<<<1, 256, 0, stream>>>((const short*)x, flag);

  if (newPath) {
    k_input2<<<(N * H + 255) / 256, 256, 0, stream>>>(x, w_in, b_in, hhi, hlo, flag, N);

    hipMemsetAsync(deg, 0, (size_t)N * sizeof(int), stream);
    k_hist<<<(E + 255) / 256, 256, 0, stream>>>(dstI, deg, E);
    k_scan_local<<<NB, 256, 0, stream>>>(deg, rowptr, bsum, N);
    k_scan_block<<<1, 256, 0, stream>>>(bsum, bexcl, NB);
    k_scan_add<<<(N + 256) / 256, 256, 0, stream>>>(rowptr, deg, bexcl, N, E);
    k_scatter<<<(E + 255) / 256, 256, 0, stream>>>(srcI, dstI, deg, srcS, E);

    const int MSG_BLOCKS = 1024;  // ~34KB LDS -> 4 blocks/CU
    for (int i = 0; i < L; ++i) {
      long oW = (long)i * H * H, oU = (long)i * 2 * H * H, oB = (long)i * H;
      k_msg2<<<MSG_BLOCKS, 256, 0, stream>>>(hhi, rowptr, srcS,
          msg_w1, msg_b1, msg_w2, msg_b2, oW, oB, agg, flag, N, ctrs + i);
      k_upd2<<<(N + 63) / 64, 256, 0, stream>>>(hhi, hlo, agg,
          upd_w1, upd_b1, upd_w2, upd_b2, bn_g, bn_b, bn_m, bn_v,
          oU, oW, oB, flag, N);
    }
    k_out2<<<(out_size + 255) / 256, 256, 0, stream>>>(hhi, hlo,
        out_w1, out_b1, out_w2, out_b2, d_out, flag, out_size);
  } else {
    // fallback: round-3 atomic path with f32 h
    const size_t hBytes   = (size_t)N * H * sizeof(float);
    const size_t aggF32B  = (size_t)N * H * sizeof(float);
    const size_t aggBf16B = (size_t)N * H * sizeof(short);
    float* hA2 = (float*)(ws + 256);
    void* agg2 = (void*)((char*)hA2 + hBytes);
    const bool af32 = (ws_size >= 256 + hBytes + aggF32B);
    const size_t aggBytes = af32 ? aggF32B : aggBf16B;
    k_input<<<(N * H + 255) / 256, 256, 0, stream>>>(x, w_in, b_in, hA2, flag, N);
    for (int i = 0; i < L; ++i) {
      long oW = (long)i * H * H, oU = (long)i * 2 * H * H, oB = (long)i * H;
      hipMemsetAsync(agg2, 0, aggBytes, stream);
      if (af32) {
        k_msg<true><<<(E + 63) / 64, 256, 0, stream>>>(hA2, srcI, dstI,
            msg_w1, msg_b1, msg_w2, msg_b2, oW, oB, agg2, flag, E);
        k_upd<true><<<(N + 63) / 64, 256, 0, stream>>>(hA2, agg2,
            upd_w1, upd_b1, upd_w2, upd_b2, bn_g, bn_b, bn_m, bn_v,
            oU, oW, oB, hA2, flag, N);
      } else {
        k_msg<false><<<(E + 63) / 64, 256, 0, stream>>>(hA2, srcI, dstI,
            msg_w1, msg_b1, msg_w2, msg_b2, oW, oB, agg2, flag, E);
        k_upd<false><<<(N + 63) / 64, 256, 0, stream>>>(hA2, agg2,
            upd_w1, upd_b1, upd_w2, upd_b2, bn_g, bn_b, bn_m, bn_v,
            oU, oW, oB, hA2, flag, N);
      }
    }
    k_out<<<(out_size + 255) / 256, 256, 0, stream>>>(hA2,
        out_w1, out_b1, out_w2, out_b2, d_out, flag, out_size);
  }
}

// Round 8
// 1014.506 us; speedup vs baseline: 1.7500x; 1.4292x over previous
//
#include <hip/hip_runtime.h>
#include <hip/hip_bf16.h>

#define H 64
#define PADW 88    // bf16 plane stride (shorts)
#define PADU 136   // bf16 plane stride K=128 (shorts)
#define PADT 68    // f32 transpose-buffer stride (floats)

typedef __attribute__((ext_vector_type(8))) short short8;
typedef __attribute__((ext_vector_type(4))) short short4v;
typedef __attribute__((ext_vector_type(4))) float floatx4;

#define MFMA(a, b, c) __builtin_amdgcn_mfma_f32_16x16x32_bf16(a, b, c, 0, 0, 0)

__device__ __forceinline__ float bf2f(short s) {
  union { unsigned int u; float f; } v;
  v.u = ((unsigned int)(unsigned short)s) << 16;
  return v.f;
}
__device__ __forceinline__ short f2bf(float f) {
  union { float f; unsigned int u; } v; v.f = f;
  unsigned int r = v.u + 0x7fffu + ((v.u >> 16) & 1u);  // RNE
  return (short)(r >> 16);
}
__device__ __forceinline__ void split2(float v, short& hi, short& lo) {
  hi = f2bf(v);
  lo = f2bf(v - bf2f(hi));
}
__device__ __forceinline__ float ldf(const void* p, long idx, bool isf32) {
  return isf32 ? ((const float*)p)[idx] : bf2f(((const short*)p)[idx]);
}

// dtype probe
__global__ void k_probe(const short* __restrict__ x, int* __restrict__ flag) {
  __shared__ int cnt;
  if (threadIdx.x == 0) cnt = 0;
  __syncthreads();
  short s = x[threadIdx.x];
  int e = (s >> 7) & 0xFF;
  int insane = (e != 0 && (e < 100 || e > 140)) ? 1 : 0;
  atomicAdd(&cnt, insane);
  __syncthreads();
  if (threadIdx.x == 0) *flag = (cnt > 64) ? 1 : 0;  // 1 = f32 inputs
}

// h0 = relu(x @ w_in + b_in) -> hi/lo planes
__global__ void k_input2(const void* __restrict__ x, const void* __restrict__ w,
                         const void* __restrict__ b, short* __restrict__ hhi,
                         short* __restrict__ hlo, const int* __restrict__ flag, int N) {
  bool isf32 = (*flag != 0);
  int idx = blockIdx.x * 256 + threadIdx.x;
  if (idx >= N * H) return;
  int v = idx >> 6, k = idx & 63;
  float acc = ldf(b, k, isf32);
#pragma unroll
  for (int d = 0; d < 3; ++d)
    acc += ldf(x, (long)v * 3 + d, isf32) * ldf(w, d * 64 + k, isf32);
  float r = fmaxf(acc, 0.f);
  short hi, lo; split2(r, hi, lo);
  hhi[idx] = hi; hlo[idx] = lo;
}

// ---------------- CSR build (counting sort by dst) ----------------

__global__ void k_hist(const int* __restrict__ dstI, int* __restrict__ deg, int E) {
  int e = blockIdx.x * 256 + threadIdx.x;
  if (e < E) atomicAdd(&deg[dstI[e]], 1);
}

__global__ void k_scan_local(const int* __restrict__ deg, int* __restrict__ rowptr,
                             int* __restrict__ bsum, int N) {
  __shared__ int s[256];
  int tid = threadIdx.x;
  int base = blockIdx.x * 1024 + tid * 4;
  int v0 = (base + 0 < N) ? deg[base + 0] : 0;
  int v1 = (base + 1 < N) ? deg[base + 1] : 0;
  int v2 = (base + 2 < N) ? deg[base + 2] : 0;
  int v3 = (base + 3 < N) ? deg[base + 3] : 0;
  int tsum = v0 + v1 + v2 + v3;
  s[tid] = tsum;
  __syncthreads();
  for (int off = 1; off < 256; off <<= 1) {
    int x = (tid >= off) ? s[tid - off] : 0;
    __syncthreads();
    s[tid] += x;
    __syncthreads();
  }
  int excl = s[tid] - tsum;
  if (base + 0 < N) rowptr[base + 0] = excl;
  if (base + 1 < N) rowptr[base + 1] = excl + v0;
  if (base + 2 < N) rowptr[base + 2] = excl + v0 + v1;
  if (base + 3 < N) rowptr[base + 3] = excl + v0 + v1 + v2;
  if (tid == 255) bsum[blockIdx.x] = s[255];
}

__global__ void k_scan_block(const int* __restrict__ bsum, int* __restrict__ bexcl, int nb) {
  __shared__ int s[256];
  int tid = threadIdx.x;
  int v = (tid < nb) ? bsum[tid] : 0;
  s[tid] = v;
  __syncthreads();
  for (int off = 1; off < 256; off <<= 1) {
    int x = (tid >= off) ? s[tid - off] : 0;
    __syncthreads();
    s[tid] += x;
    __syncthreads();
  }
  bexcl[tid] = s[tid] - v;
}

__global__ void k_scan_add(int* __restrict__ rowptr, int* __restrict__ cursor,
                           const int* __restrict__ bexcl, int N, int E) {
  int i = blockIdx.x * 256 + threadIdx.x;
  if (i < N) {
    int v = rowptr[i] + bexcl[i >> 10];
    rowptr[i] = v;
    cursor[i] = v;
  }
  if (i == N) rowptr[N] = E;
}

__global__ void k_scatter(const int* __restrict__ srcI, const int* __restrict__ dstI,
                          int* __restrict__ cursor, int* __restrict__ srcS, int E) {
  int e = blockIdx.x * 256 + threadIdx.x;
  if (e >= E) return;
  int d = dstI[e];
  int p = atomicAdd(&cursor[d], 1);
  srcS[p] = srcI[e];
}

// ---------------- dense per-node message MLP ----------------
// M[s] = relu(h[s] @ W1 + b1) @ W2  (b2 deferred to k_gather as deg*b2).
// Full hi/lo split precision; M written bf16. 16 nodes/wave, 4 waves/block.
__global__ __launch_bounds__(256) void k_mlp(
    const short* __restrict__ hhi, const short* __restrict__ hlo,
    const void* __restrict__ W1, const void* __restrict__ B1,
    const void* __restrict__ W2, long oW, long oB,
    short* __restrict__ M, const int* __restrict__ flag, int N) {
  __shared__ short w1hi[64 * PADW], w1lo[64 * PADW];
  __shared__ short w2hi[64 * PADW], w2lo[64 * PADW];
  __shared__ float b1s[64];
  __shared__ float tbuf[4][16 * PADT];

  bool isf32 = (*flag != 0);
  int tid = threadIdx.x;
  for (int idx = tid; idx < 4096; idx += 256) {
    int j = idx >> 6, k = idx & 63;  // W[j=in][k=out] row-major -> plane[out][in]
    short hi, lo;
    split2(ldf(W1, oW + idx, isf32), hi, lo);
    w1hi[k * PADW + j] = hi; w1lo[k * PADW + j] = lo;
    split2(ldf(W2, oW + idx, isf32), hi, lo);
    w2hi[k * PADW + j] = hi; w2lo[k * PADW + j] = lo;
  }
  if (tid < 64) b1s[tid] = ldf(B1, oB + tid, isf32);
  __syncthreads();

  const int wave = tid >> 6, lane = tid & 63;
  const int m = lane & 15, quad = lane >> 4;
  const int nBase = (blockIdx.x * 4 + wave) * 16;
  int node = nBase + m;
  int nc = node < N ? node : N - 1;

  short8 fhi[2], flo[2];
  fhi[0] = *(const short8*)(hhi + (long)nc * H + quad * 8);
  fhi[1] = *(const short8*)(hhi + (long)nc * H + 32 + quad * 8);
  flo[0] = *(const short8*)(hlo + (long)nc * H + quad * 8);
  flo[1] = *(const short8*)(hlo + (long)nc * H + 32 + quad * 8);

  floatx4 acc[4];
#pragma unroll
  for (int t = 0; t < 4; ++t) acc[t] = (floatx4){0.f, 0.f, 0.f, 0.f};
#pragma unroll
  for (int t = 0; t < 4; ++t) {
    const short* whi = &w1hi[(t * 16 + m) * PADW + quad * 8];
    const short* wlo = &w1lo[(t * 16 + m) * PADW + quad * 8];
    acc[t] = MFMA(fhi[0], *(const short8*)(whi), acc[t]);
    acc[t] = MFMA(fhi[1], *(const short8*)(whi + 32), acc[t]);
    acc[t] = MFMA(flo[0], *(const short8*)(whi), acc[t]);
    acc[t] = MFMA(flo[1], *(const short8*)(whi + 32), acc[t]);
    acc[t] = MFMA(fhi[0], *(const short8*)(wlo), acc[t]);
    acc[t] = MFMA(fhi[1], *(const short8*)(wlo + 32), acc[t]);
  }

  float* tb = tbuf[wave];
#pragma unroll
  for (int t = 0; t < 4; ++t) {
    int col = t * 16 + m;
    float bb = b1s[col];
#pragma unroll
    for (int r = 0; r < 4; ++r)
      tb[(quad * 4 + r) * PADT + col] = fmaxf(acc[t][r] + bb, 0.f);
  }
  __syncthreads();

  float av[16];
  *(floatx4*)(av + 0)  = *(const floatx4*)(&tb[m * PADT + quad * 8]);
  *(floatx4*)(av + 4)  = *(const floatx4*)(&tb[m * PADT + quad * 8 + 4]);
  *(floatx4*)(av + 8)  = *(const floatx4*)(&tb[m * PADT + 32 + quad * 8]);
  *(floatx4*)(av + 12) = *(const floatx4*)(&tb[m * PADT + 32 + quad * 8 + 4]);
  short8 thi0, tlo0, thi1, tlo1;
#pragma unroll
  for (int j = 0; j < 8; ++j) {
    short hi, lo;
    split2(av[j], hi, lo);     thi0[j] = hi; tlo0[j] = lo;
    split2(av[8 + j], hi, lo); thi1[j] = hi; tlo1[j] = lo;
  }

  floatx4 mac[4];
#pragma unroll
  for (int t = 0; t < 4; ++t) mac[t] = (floatx4){0.f, 0.f, 0.f, 0.f};
#pragma unroll
  for (int t = 0; t < 4; ++t) {
    const short* whi = &w2hi[(t * 16 + m) * PADW + quad * 8];
    const short* wlo = &w2lo[(t * 16 + m) * PADW + quad * 8];
    mac[t] = MFMA(thi0, *(const short8*)(whi), mac[t]);
    mac[t] = MFMA(thi1, *(const short8*)(whi + 32), mac[t]);
    mac[t] = MFMA(tlo0, *(const short8*)(whi), mac[t]);
    mac[t] = MFMA(tlo1, *(const short8*)(whi + 32), mac[t]);
    mac[t] = MFMA(thi0, *(const short8*)(wlo), mac[t]);
    mac[t] = MFMA(thi1, *(const short8*)(wlo + 32), mac[t]);
  }

#pragma unroll
  for (int t = 0; t < 4; ++t) {
    int col = t * 16 + m;
#pragma unroll
    for (int r = 0; r < 4; ++r) {
      int nrow = nBase + quad * 4 + r;
      if (nrow < N) M[(long)nrow * H + col] = f2bf(mac[t][r]);
    }
  }
}

// ---------------- gather-sum: agg[d] = sum_seg M[src] + deg*b2 ----------------
// 4 node-streams per wave; 16 lanes cover a 128B bf16 row; 4-edge unroll.
__global__ __launch_bounds__(256) void k_gather(
    const short* __restrict__ M, const int* __restrict__ rowptr,
    const int* __restrict__ srcS, const void* __restrict__ B2, long oB,
    short* __restrict__ agg, const int* __restrict__ flag, int N, int totWaves) {
  __shared__ float b2s[64];
  bool isf32 = (*flag != 0);
  if (threadIdx.x < 64) b2s[threadIdx.x] = ldf(B2, oB + threadIdx.x, isf32);
  __syncthreads();
  const int wave = threadIdx.x >> 6, lane = threadIdx.x & 63;
  const int g = lane >> 4, l = lane & 15;
  float b2v[4];
#pragma unroll
  for (int j = 0; j < 4; ++j) b2v[j] = b2s[l * 4 + j];

  const int gw = blockIdx.x * 4 + wave;
  const int nTask = (N + 3) >> 2;
  for (int task = gw; task < nTask; task += totWaves) {
    int n = task * 4 + g;
    bool valid = n < N;
    int nc = valid ? n : N - 1;
    int rs = rowptr[nc], re = rowptr[nc + 1];
    if (!valid) { rs = 0; re = 0; }
    float a0 = 0.f, a1 = 0.f, a2 = 0.f, a3 = 0.f;
    for (int e = rs; e < re; e += 4) {
      int c1 = e + 1 < re ? e + 1 : re - 1;
      int c2 = e + 2 < re ? e + 2 : re - 1;
      int c3 = e + 3 < re ? e + 3 : re - 1;
      int s0 = srcS[e], s1 = srcS[c1], s2 = srcS[c2], s3 = srcS[c3];
      short4v r0 = *(const short4v*)(M + (long)s0 * H + l * 4);
      short4v r1 = *(const short4v*)(M + (long)s1 * H + l * 4);
      short4v r2 = *(const short4v*)(M + (long)s2 * H + l * 4);
      short4v r3 = *(const short4v*)(M + (long)s3 * H + l * 4);
      a0 += bf2f(r0[0]); a1 += bf2f(r0[1]); a2 += bf2f(r0[2]); a3 += bf2f(r0[3]);
      if (e + 1 < re) { a0 += bf2f(r1[0]); a1 += bf2f(r1[1]); a2 += bf2f(r1[2]); a3 += bf2f(r1[3]); }
      if (e + 2 < re) { a0 += bf2f(r2[0]); a1 += bf2f(r2[1]); a2 += bf2f(r2[2]); a3 += bf2f(r2[3]); }
      if (e + 3 < re) { a0 += bf2f(r3[0]); a1 += bf2f(r3[1]); a2 += bf2f(r3[2]); a3 += bf2f(r3[3]); }
    }
    if (valid) {
      float dv = (float)(re - rs);
      short4v o;
      o[0] = f2bf(a0 + dv * b2v[0]);
      o[1] = f2bf(a1 + dv * b2v[1]);
      o[2] = f2bf(a2 + dv * b2v[2]);
      o[3] = f2bf(a3 + dv * b2v[3]);
      *(short4v*)(agg + (long)n * H + l * 4) = o;
    }
  }
}

// ---------------- update kernel (round-5 proven; agg now bf16 plane) ----------------
__global__ __launch_bounds__(256) void k_upd2(
    short* __restrict__ hhi, short* __restrict__ hlo, const short* __restrict__ agg,
    const void* __restrict__ W1, const void* __restrict__ B1,
    const void* __restrict__ W2, const void* __restrict__ B2,
    const void* __restrict__ G, const void* __restrict__ Bb,
    const void* __restrict__ Mm, const void* __restrict__ Vv,
    long oU, long oW, long oB, const int* __restrict__ flag, int N) {
  __shared__ short w1hi[64 * PADU], w1lo[64 * PADU];
  __shared__ short w2hi[64 * PADW], w2lo[64 * PADW];
  __shared__ float b1s[64], b2s[64], scl[64], sft[64];
  __shared__ float tbuf[4][16 * PADT];

  bool isf32 = (*flag != 0);
  int tid = threadIdx.x;
  for (int idx = tid; idx < 8192; idx += 256) {
    int j = idx >> 6, k = idx & 63;
    short hi, lo;
    split2(ldf(W1, oU + idx, isf32), hi, lo);
    w1hi[k * PADU + j] = hi; w1lo[k * PADU + j] = lo;
  }
  for (int idx = tid; idx < 4096; idx += 256) {
    int j = idx >> 6, k = idx & 63;
    short hi, lo;
    split2(ldf(W2, oW + idx, isf32), hi, lo);
    w2hi[k * PADW + j] = hi; w2lo[k * PADW + j] = lo;
  }
  if (tid < 64) {
    b1s[tid] = ldf(B1, oB + tid, isf32);
    b2s[tid] = ldf(B2, oB + tid, isf32);
    float s = ldf(G, oB + tid, isf32) * rsqrtf(ldf(Vv, oB + tid, isf32) + 1e-5f);
    scl[tid] = s;
    sft[tid] = ldf(Bb, oB + tid, isf32) - ldf(Mm, oB + tid, isf32) * s;
  }
  __syncthreads();

  const int wave = tid >> 6, lane = tid & 63;
  const int m = lane & 15, quad = lane >> 4;
  const int nBase = (blockIdx.x * 4 + wave) * 16;
  int node = nBase + m;
  int nc = node < N ? node : N - 1;

  short8 fhi[4], flo[2];
  fhi[0] = *(const short8*)(hhi + (long)nc * H + quad * 8);
  fhi[1] = *(const short8*)(hhi + (long)nc * H + 32 + quad * 8);
  flo[0] = *(const short8*)(hlo + (long)nc * H + quad * 8);
  flo[1] = *(const short8*)(hlo + (long)nc * H + 32 + quad * 8);
  fhi[2] = *(const short8*)(agg + (long)nc * H + quad * 8);
  fhi[3] = *(const short8*)(agg + (long)nc * H + 32 + quad * 8);

  floatx4 acc[4];
#pragma unroll
  for (int t = 0; t < 4; ++t) acc[t] = (floatx4){0.f, 0.f, 0.f, 0.f};
#pragma unroll
  for (int t = 0; t < 4; ++t) {
    const short* whi = &w1hi[(t * 16 + m) * PADU + quad * 8];
    const short* wlo = &w1lo[(t * 16 + m) * PADU + quad * 8];
#pragma unroll
    for (int c = 0; c < 4; ++c) {
      acc[t] = MFMA(fhi[c], *(const short8*)(whi + 32 * c), acc[t]);
      if (c < 2) acc[t] = MFMA(flo[c], *(const short8*)(whi + 32 * c), acc[t]);
      acc[t] = MFMA(fhi[c], *(const short8*)(wlo + 32 * c), acc[t]);
    }
  }

  float* tb = tbuf[wave];
#pragma unroll
  for (int t = 0; t < 4; ++t) {
    int col = t * 16 + m;
    float bb = b1s[col];
#pragma unroll
    for (int r = 0; r < 4; ++r)
      tb[(quad * 4 + r) * PADT + col] = fmaxf(acc[t][r] + bb, 0.f);
  }
  __syncthreads();

  float av[16];
  *(floatx4*)(av + 0)  = *(const floatx4*)(&tb[m * PADT + quad * 8]);
  *(floatx4*)(av + 4)  = *(const floatx4*)(&tb[m * PADT + quad * 8 + 4]);
  *(floatx4*)(av + 8)  = *(const floatx4*)(&tb[m * PADT + 32 + quad * 8]);
  *(floatx4*)(av + 12) = *(const floatx4*)(&tb[m * PADT + 32 + quad * 8 + 4]);
  short8 thi0, tlo0, thi1, tlo1;
#pragma unroll
  for (int j = 0; j < 8; ++j) {
    short hi, lo;
    split2(av[j], hi, lo);     thi0[j] = hi; tlo0[j] = lo;
    split2(av[8 + j], hi, lo); thi1[j] = hi; tlo1[j] = lo;
  }

  floatx4 mac[4];
#pragma unroll
  for (int t = 0; t < 4; ++t) mac[t] = (floatx4){0.f, 0.f, 0.f, 0.f};
#pragma unroll
  for (int t = 0; t < 4; ++t) {
    const short* whi = &w2hi[(t * 16 + m) * PADW + quad * 8];
    const short* wlo = &w2lo[(t * 16 + m) * PADW + quad * 8];
    mac[t] = MFMA(thi0, *(const short8*)(whi), mac[t]);
    mac[t] = MFMA(thi1, *(const short8*)(whi + 32), mac[t]);
    mac[t] = MFMA(tlo0, *(const short8*)(whi), mac[t]);
    mac[t] = MFMA(tlo1, *(const short8*)(whi + 32), mac[t]);
    mac[t] = MFMA(thi0, *(const short8*)(wlo), mac[t]);
    mac[t] = MFMA(thi1, *(const short8*)(wlo + 32), mac[t]);
  }

#pragma unroll
  for (int t = 0; t < 4; ++t) {
    int col = t * 16 + m;
    float bb = b2s[col], ss = scl[col], ff = sft[col];
#pragma unroll
    for (int r = 0; r < 4; ++r) {
      int nrow = nBase + quad * 4 + r;
      if (nrow < N) {
        long el = (long)nrow * H + col;
        float hv = (mac[t][r] + bb) * ss + ff;
        float ho = bf2f(hhi[el]) + bf2f(hlo[el]);
        float hn = fmaxf(hv + ho, 0.f);
        short hi2, lo2; split2(hn, hi2, lo2);
        hhi[el] = hi2; hlo[el] = lo2;
      }
    }
  }
}

// readout from hi/lo planes
__global__ __launch_bounds__(256) void k_out2(
    const short* __restrict__ hhi, const short* __restrict__ hlo,
    const void* __restrict__ W1, const void* __restrict__ B1,
    const void* __restrict__ W2, const void* __restrict__ B2,
    void* __restrict__ out, const int* __restrict__ flag, int NQ) {
  __shared__ float w1s[64 * 32];
  __shared__ float b1sh[32], w2s[32];
  bool isf32 = (*flag != 0);
  int tid = threadIdx.x;
  for (int idx = tid; idx < 2048; idx += 256) w1s[idx] = ldf(W1, idx, isf32);
  if (tid < 32) { b1sh[tid] = ldf(B1, tid, isf32); w2s[tid] = ldf(W2, tid, isf32); }
  __syncthreads();
  int v = blockIdx.x * 256 + tid;
  if (v >= NQ) return;
  float hr[64];
#pragma unroll
  for (int j = 0; j < 64; ++j)
    hr[j] = bf2f(hhi[(long)v * H + j]) + bf2f(hlo[(long)v * H + j]);
  float accum = ldf(B2, 0, isf32);
#pragma unroll 4
  for (int k = 0; k < 32; ++k) {
    float t = b1sh[k];
#pragma unroll
    for (int j = 0; j < 64; ++j) t += hr[j] * w1s[j * 32 + k];
    accum += fmaxf(t, 0.f) * w2s[k];
  }
  if (isf32) ((float*)out)[v] = accum;
  else ((short*)out)[v] = f2bf(accum);
}

// ---------------- old fallback path (round-3, f32 h) ----------------

__global__ void k_input(const void* __restrict__ x, const void* __restrict__ w,
                        const void* __restrict__ b, float* __restrict__ h,
                        const int* __restrict__ flag, int N) {
  bool isf32 = (*flag != 0);
  int idx = blockIdx.x * 256 + threadIdx.x;
  if (idx >= N * H) return;
  int v = idx >> 6, k = idx & 63;
  float acc = ldf(b, k, isf32);
#pragma unroll
  for (int d = 0; d < 3; ++d)
    acc += ldf(x, (long)v * 3 + d, isf32) * ldf(w, d * 64 + k, isf32);
  h[idx] = fmaxf(acc, 0.f);
}

template <bool AF32>
__global__ __launch_bounds__(256) void k_msg(
    const float* __restrict__ h, const int* __restrict__ srcI, const int* __restrict__ dstI,
    const void* __restrict__ W1, const void* __restrict__ B1,
    const void* __restrict__ W2, const void* __restrict__ B2,
    long oW, long oB,
    void* __restrict__ aggv, const int* __restrict__ flag, int E) {
  __shared__ short w1hi[64 * PADW], w1lo[64 * PADW];
  __shared__ short w2hi[64 * PADW], w2lo[64 * PADW];
  __shared__ float b1s[64], b2s[64];
  __shared__ float tbuf[4][16 * PADT];

  bool isf32 = (*flag != 0);
  int tid = threadIdx.x;
  for (int idx = tid; idx < 4096; idx += 256) {
    int j = idx >> 6, k = idx & 63;
    short hi, lo;
    split2(ldf(W1, oW + idx, isf32), hi, lo);
    w1hi[k * PADW + j] = hi; w1lo[k * PADW + j] = lo;
    split2(ldf(W2, oW + idx, isf32), hi, lo);
    w2hi[k * PADW + j] = hi; w2lo[k * PADW + j] = lo;
  }
  if (tid < 64) {
    b1s[tid] = ldf(B1, oB + tid, isf32);
    b2s[tid] = ldf(B2, oB + tid, isf32);
  }
  __syncthreads();

  const int wave = tid >> 6, lane = tid & 63;
  const int m = lane & 15, quad = lane >> 4;
  const int eBase = (blockIdx.x * 4 + wave) * 16;

  int e = eBase + m;
  int ec = e < E ? e : E - 1;
  int sv = srcI[ec];
  int dv = dstI[ec];

  const float* hrow = h + (long)sv * H;
  float av[16];
  *(floatx4*)(av + 0)  = *(const floatx4*)(hrow + quad * 8);
  *(floatx4*)(av + 4)  = *(const floatx4*)(hrow + quad * 8 + 4);
  *(floatx4*)(av + 8)  = *(const floatx4*)(hrow + 32 + quad * 8);
  *(floatx4*)(av + 12) = *(const floatx4*)(hrow + 32 + quad * 8 + 4);
  short8 ahi0, alo0, ahi1, alo1;
#pragma unroll
  for (int j = 0; j < 8; ++j) {
    short hi, lo;
    split2(av[j], hi, lo);     ahi0[j] = hi; alo0[j] = lo;
    split2(av[8 + j], hi, lo); ahi1[j] = hi; alo1[j] = lo;
  }

  floatx4 acc[4];
#pragma unroll
  for (int t = 0; t < 4; ++t) acc[t] = (floatx4){0.f, 0.f, 0.f, 0.f};
#pragma unroll
  for (int t = 0; t < 4; ++t) {
    const short* whi = &w1hi[(t * 16 + m) * PADW + quad * 8];
    const short* wlo = &w1lo[(t * 16 + m) * PADW + quad * 8];
    acc[t] = MFMA(ahi0, *(const short8*)(whi), acc[t]);
    acc[t] = MFMA(ahi1, *(const short8*)(whi + 32), acc[t]);
    acc[t] = MFMA(alo0, *(const short8*)(whi), acc[t]);
    acc[t] = MFMA(alo1, *(const short8*)(whi + 32), acc[t]);
    acc[t] = MFMA(ahi0, *(const short8*)(wlo), acc[t]);
    acc[t] = MFMA(ahi1, *(const short8*)(wlo + 32), acc[t]);
  }

  float* tbf = tbuf[wave];
#pragma unroll
  for (int t = 0; t < 4; ++t) {
    int col = t * 16 + m;
    float bb = b1s[col];
#pragma unroll
    for (int r = 0; r < 4; ++r)
      tbf[(quad * 4 + r) * PADT + col] = fmaxf(acc[t][r] + bb, 0.f);
  }
  __syncthreads();

  *(floatx4*)(av + 0)  = *(const floatx4*)(&tbf[m * PADT + quad * 8]);
  *(floatx4*)(av + 4)  = *(const floatx4*)(&tbf[m * PADT + quad * 8 + 4]);
  *(floatx4*)(av + 8)  = *(const floatx4*)(&tbf[m * PADT + 32 + quad * 8]);
  *(floatx4*)(av + 12) = *(const floatx4*)(&tbf[m * PADT + 32 + quad * 8 + 4]);
#pragma unroll
  for (int j = 0; j < 8; ++j) {
    short hi, lo;
    split2(av[j], hi, lo);     ahi0[j] = hi; alo0[j] = lo;
    split2(av[8 + j], hi, lo); ahi1[j] = hi; alo1[j] = lo;
  }

  floatx4 mac[4];
#pragma unroll
  for (int t = 0; t < 4; ++t) mac[t] = (floatx4){0.f, 0.f, 0.f, 0.f};
#pragma unroll
  for (int t = 0; t < 4; ++t) {
    const short* whi = &w2hi[(t * 16 + m) * PADW + quad * 8];
    const short* wlo = &w2lo[(t * 16 + m) * PADW + quad * 8];
    mac[t] = MFMA(ahi0, *(const short8*)(whi), mac[t]);
    mac[t] = MFMA(ahi1, *(const short8*)(whi + 32), mac[t]);
    mac[t] = MFMA(alo0, *(const short8*)(whi), mac[t]);
    mac[t] = MFMA(alo1, *(const short8*)(whi + 32), mac[t]);
    mac[t] = MFMA(ahi0, *(const short8*)(wlo), mac[t]);
    mac[t] = MFMA(ahi1, *(const short8*)(wlo + 32), mac[t]);
  }

  float* aggF = (float*)aggv;
  short* aggS = (short*)aggv;
#pragma unroll
  for (int t = 0; t < 4; ++t) {
    int col = t * 16 + m;
    float bb = b2s[col];
#pragma unroll
    for (int r = 0; r < 4; ++r) {
      int row = quad * 4 + r;
      int er = eBase + row;
      int dr = __shfl(dv, row);
      float v = mac[t][r] + bb;
      if (AF32) {
        if (er < E) atomicAdd(&aggF[(long)dr * H + col], v);
      } else {
        float v2 = __shfl_down(v, 1);
        if (((m & 1) == 0) && er < E) {
          unsigned int pk = ((unsigned int)(unsigned short)f2bf(v2) << 16) |
                            (unsigned int)(unsigned short)f2bf(v);
          unsafeAtomicAdd((__hip_bfloat162*)&aggS[(long)dr * H + col],
                          *(__hip_bfloat162*)&pk);
        }
      }
    }
  }
}

template <bool AF32>
__global__ __launch_bounds__(256) void k_upd(
    const float* __restrict__ h, const void* __restrict__ aggv,
    const void* __restrict__ W1, const void* __restrict__ B1,
    const void* __restrict__ W2, const void* __restrict__ B2,
    const void* __restrict__ G, const void* __restrict__ Bb,
    const void* __restrict__ Mm, const void* __restrict__ Vv,
    long oU, long oW, long oB,
    float* __restrict__ hout, const int* __restrict__ flag, int N) {
  __shared__ short w1hi[64 * PADU], w1lo[64 * PADU];
  __shared__ short w2hi[64 * PADW], w2lo[64 * PADW];
  __shared__ float b1s[64], b2s[64], scl[64], sft[64];
  __shared__ float tbuf[4][16 * PADT];

  bool isf32 = (*flag != 0);
  int tid = threadIdx.x;
  for (int idx = tid; idx < 8192; idx += 256) {
    int j = idx >> 6, k = idx & 63;
    short hi, lo;
    split2(ldf(W1, oU + idx, isf32), hi, lo);
    w1hi[k * PADU + j] = hi; w1lo[k * PADU + j] = lo;
  }
  for (int idx = tid; idx < 4096; idx += 256) {
    int j = idx >> 6, k = idx & 63;
    short hi, lo;
    split2(ldf(W2, oW + idx, isf32), hi, lo);
    w2hi[k * PADW + j] = hi; w2lo[k * PADW + j] = lo;
  }
  if (tid < 64) {
    b1s[tid] = ldf(B1, oB + tid, isf32);
    b2s[tid] = ldf(B2, oB + tid, isf32);
    float s = ldf(G, oB + tid, isf32) * rsqrtf(ldf(Vv, oB + tid, isf32) + 1e-5f);
    scl[tid] = s;
    sft[tid] = ldf(Bb, oB + tid, isf32) - ldf(Mm, oB + tid, isf32) * s;
  }
  __syncthreads();

  const int wave = tid >> 6, lane = tid & 63;
  const int m = lane & 15, quad = lane >> 4;
  const int nBase = (blockIdx.x * 4 + wave) * 16;
  int node = nBase + m;
  int nc = node < N ? node : N - 1;

  float av[16];
  const float* hrow = h + (long)nc * H;
  *(floatx4*)(av + 0)  = *(const floatx4*)(hrow + quad * 8);
  *(floatx4*)(av + 4)  = *(const floatx4*)(hrow + quad * 8 + 4);
  *(floatx4*)(av + 8)  = *(const floatx4*)(hrow + 32 + quad * 8);
  *(floatx4*)(av + 12) = *(const floatx4*)(hrow + 32 + quad * 8 + 4);
  float gv[16];
  if (AF32) {
    const float* arow = (const float*)aggv + (long)nc * H;
    *(floatx4*)(gv + 0)  = *(const floatx4*)(arow + quad * 8);
    *(floatx4*)(gv + 4)  = *(const floatx4*)(arow + quad * 8 + 4);
    *(floatx4*)(gv + 8)  = *(const floatx4*)(arow + 32 + quad * 8);
    *(floatx4*)(gv + 12) = *(const floatx4*)(arow + 32 + quad * 8 + 4);
  } else {
    const short* arow = (const short*)aggv + (long)nc * H;
#pragma unroll
    for (int j = 0; j < 8; ++j) {
      gv[j] = bf2f(arow[quad * 8 + j]);
      gv[8 + j] = bf2f(arow[32 + quad * 8 + j]);
    }
  }
  short8 fhi[4], flo[4];
#pragma unroll
  for (int j = 0; j < 8; ++j) {
    short hi, lo;
    split2(av[j], hi, lo);      fhi[0][j] = hi; flo[0][j] = lo;
    split2(av[8 + j], hi, lo);  fhi[1][j] = hi; flo[1][j] = lo;
    split2(gv[j], hi, lo);      fhi[2][j] = hi; flo[2][j] = lo;
    split2(gv[8 + j], hi, lo);  fhi[3][j] = hi; flo[3][j] = lo;
  }

  floatx4 acc[4];
#pragma unroll
  for (int t = 0; t < 4; ++t) acc[t] = (floatx4){0.f, 0.f, 0.f, 0.f};
#pragma unroll
  for (int t = 0; t < 4; ++t) {
    const short* whi = &w1hi[(t * 16 + m) * PADU + quad * 8];
    const short* wlo = &w1lo[(t * 16 + m) * PADU + quad * 8];
#pragma unroll
    for (int c = 0; c < 4; ++c) {
      acc[t] = MFMA(fhi[c], *(const short8*)(whi + 32 * c), acc[t]);
      acc[t] = MFMA(flo[c], *(const short8*)(whi + 32 * c), acc[t]);
      acc[t] = MFMA(fhi[c], *(const short8*)(wlo + 32 * c), acc[t]);
    }
  }

  float* tbf = tbuf[wave];
#pragma unroll
  for (int t = 0; t < 4; ++t) {
    int col = t * 16 + m;
    float bb = b1s[col];
#pragma unroll
    for (int r = 0; r < 4; ++r)
      tbf[(quad * 4 + r) * PADT + col] = fmaxf(acc[t][r] + bb, 0.f);
  }
  __syncthreads();

  *(floatx4*)(av + 0)  = *(const floatx4*)(&tbf[m * PADT + quad * 8]);
  *(floatx4*)(av + 4)  = *(const floatx4*)(&tbf[m * PADT + quad * 8 + 4]);
  *(floatx4*)(av + 8)  = *(const floatx4*)(&tbf[m * PADT + 32 + quad * 8]);
  *(floatx4*)(av + 12) = *(const floatx4*)(&tbf[m * PADT + 32 + quad * 8 + 4]);
  short8 thi0, tlo0, thi1, tlo1;
#pragma unroll
  for (int j = 0; j < 8; ++j) {
    short hi, lo;
    split2(av[j], hi, lo);     thi0[j] = hi; tlo0[j] = lo;
    split2(av[8 + j], hi, lo); thi1[j] = hi; tlo1[j] = lo;
  }

  floatx4 mac[4];
#pragma unroll
  for (int t = 0; t < 4; ++t) mac[t] = (floatx4){0.f, 0.f, 0.f, 0.f};
#pragma unroll
  for (int t = 0; t < 4; ++t) {
    const short* whi = &w2hi[(t * 16 + m) * PADW + quad * 8];
    const short* wlo = &w2lo[(t * 16 + m) * PADW + quad * 8];
    mac[t] = MFMA(thi0, *(const short8*)(whi), mac[t]);
    mac[t] = MFMA(thi1, *(const short8*)(whi + 32), mac[t]);
    mac[t] = MFMA(tlo0, *(const short8*)(whi), mac[t]);
    mac[t] = MFMA(tlo1, *(const short8*)(whi + 32), mac[t]);
    mac[t] = MFMA(thi0, *(const short8*)(wlo), mac[t]);
    mac[t] = MFMA(thi1, *(const short8*)(wlo + 32), mac[t]);
  }

#pragma unroll
  for (int t = 0; t < 4; ++t) {
    int col = t * 16 + m;
    float bb = b2s[col], ss = scl[col], ff = sft[col];
#pragma unroll
    for (int r = 0; r < 4; ++r) {
      int nrow = nBase + quad * 4 + r;
      if (nrow < N) {
        float hv = (mac[t][r] + bb) * ss + ff;
        float ho = h[(long)nrow * H + col];
        hout[(long)nrow * H + col] = fmaxf(hv + ho, 0.f);
      }
    }
  }
}

__global__ __launch_bounds__(256) void k_out(
    const float* __restrict__ h, const void* __restrict__ W1, const void* __restrict__ B1,
    const void* __restrict__ W2, const void* __restrict__ B2,
    void* __restrict__ out, const int* __restrict__ flag, int NQ) {
  __shared__ float w1s[64 * 32];
  __shared__ float b1sh[32], w2s[32];
  bool isf32 = (*flag != 0);
  int tid = threadIdx.x;
  for (int idx = tid; idx < 2048; idx += 256) w1s[idx] = ldf(W1, idx, isf32);
  if (tid < 32) { b1sh[tid] = ldf(B1, tid, isf32); w2s[tid] = ldf(W2, tid, isf32); }
  __syncthreads();
  int v = blockIdx.x * 256 + tid;
  if (v >= NQ) return;
  float hr[64];
  const float* hp = h + (long)v * H;
#pragma unroll
  for (int j = 0; j < 64; ++j) hr[j] = hp[j];
  float accum = ldf(B2, 0, isf32);
#pragma unroll 4
  for (int k = 0; k < 32; ++k) {
    float t = b1sh[k];
#pragma unroll
    for (int j = 0; j < 64; ++j) t += hr[j] * w1s[j * 32 + k];
    accum += fmaxf(t, 0.f) * w2s[k];
  }
  if (isf32) ((float*)out)[v] = accum;
  else ((short*)out)[v] = f2bf(accum);
}

extern "C" void kernel_launch(void* const* d_in, const int* in_sizes, int n_in,
                              void* d_out, int out_size, void* d_ws, size_t ws_size,
                              hipStream_t stream) {
  const void* x      = d_in[0];
  const int*  ei     = (const int*)d_in[1];
  const void* w_in   = d_in[3];
  const void* b_in   = d_in[4];
  const void* msg_w1 = d_in[5];
  const void* msg_b1 = d_in[6];
  const void* msg_w2 = d_in[7];
  const void* msg_b2 = d_in[8];
  const void* upd_w1 = d_in[9];
  const void* upd_b1 = d_in[10];
  const void* upd_w2 = d_in[11];
  const void* upd_b2 = d_in[12];
  const void* bn_g   = d_in[13];
  const void* bn_b   = d_in[14];
  const void* bn_m   = d_in[15];
  const void* bn_v   = d_in[16];
  const void* out_w1 = d_in[17];
  const void* out_b1 = d_in[18];
  const void* out_w2 = d_in[19];
  const void* out_b2 = d_in[20];

  const int N = in_sizes[0] / 3;
  const int E = in_sizes[1] / 2;
  const int L = in_sizes[5] / (H * H);
  const int* srcI = ei;
  const int* dstI = ei + E;

  // workspace layout (256B-aligned slots)
  size_t off = 0;
  auto alloc = [&](size_t bytes) { size_t o = off; off += (bytes + 255) & ~(size_t)255; return o; };
  size_t o_flag   = alloc(256);
  size_t o_hhi    = alloc((size_t)N * H * sizeof(short));
  size_t o_hlo    = alloc((size_t)N * H * sizeof(short));
  size_t o_agg    = alloc((size_t)N * H * sizeof(short));   // bf16 agg plane
  size_t o_M      = alloc((size_t)N * H * sizeof(short));   // bf16 message table
  size_t o_rowptr = alloc((size_t)(N + 1) * sizeof(int));
  size_t o_cursor = alloc((size_t)N * sizeof(int));
  size_t o_bsum   = alloc(256 * sizeof(int));
  size_t o_bexcl  = alloc(256 * sizeof(int));
  size_t o_srcS   = alloc((size_t)E * sizeof(int));
  const size_t needNew = off;
  const int NB = (N + 1023) >> 10;
  const bool newPath = (ws_size >= needNew) && (NB <= 256);

  char* ws = (char*)d_ws;
  int*   flag   = (int*)(ws + o_flag);
  short* hhi    = (short*)(ws + o_hhi);
  short* hlo    = (short*)(ws + o_hlo);
  short* aggS   = (short*)(ws + o_agg);
  short* Mbuf   = (short*)(ws + o_M);
  int*   rowptr = (int*)(ws + o_rowptr);
  int*   deg    = (int*)(ws + o_cursor);
  int*   bsum   = (int*)(ws + o_bsum);
  int*   bexcl  = (int*)(ws + o_bexcl);
  int*   srcS   = (int*)(ws + o_srcS);

  k_probe<<<1, 256, 0, stream>>>((const short*)x, flag);

  if (newPath) {
    k_input2<<<(N * H + 255) / 256, 256, 0, stream>>>(x, w_in, b_in, hhi, hlo, flag, N);

    hipMemsetAsync(deg, 0, (size_t)N * sizeof(int), stream);
    k_hist<<<(E + 255) / 256, 256, 0, stream>>>(dstI, deg, E);
    k_scan_local<<<NB, 256, 0, stream>>>(deg, rowptr, bsum, N);
    k_scan_block<<<1, 256, 0, stream>>>(bsum, bexcl, NB);
    k_scan_add<<<(N + 256) / 256, 256, 0, stream>>>(rowptr, deg, bexcl, N, E);
    k_scatter<<<(E + 255) / 256, 256, 0, stream>>>(srcI, dstI, deg, srcS, E);

    const int GB = 2048;  // gather blocks: tiny LDS -> high occupancy
    for (int i = 0; i < L; ++i) {
      long oW = (long)i * H * H, oU = (long)i * 2 * H * H, oB = (long)i * H;
      k_mlp<<<(N + 63) / 64, 256, 0, stream>>>(hhi, hlo,
          msg_w1, msg_b1, msg_w2, oW, oB, Mbuf, flag, N);
      k_gather<<<GB, 256, 0, stream>>>(Mbuf, rowptr, srcS,
          msg_b2, oB, aggS, flag, N, GB * 4);
      k_upd2<<<(N + 63) / 64, 256, 0, stream>>>(hhi, hlo, aggS,
          upd_w1, upd_b1, upd_w2, upd_b2, bn_g, bn_b, bn_m, bn_v,
          oU, oW, oB, flag, N);
    }
    k_out2<<<(out_size + 255) / 256, 256, 0, stream>>>(hhi, hlo,
        out_w1, out_b1, out_w2, out_b2, d_out, flag, out_size);
  } else {
    // fallback: round-3 atomic path with f32 h
    const size_t hBytes   = (size_t)N * H * sizeof(float);
    const size_t aggF32B  = (size_t)N * H * sizeof(float);
    const size_t aggBf16B = (size_t)N * H * sizeof(short);
    float* hA2 = (float*)(ws + 256);
    void* agg2 = (void*)((char*)hA2 + hBytes);
    const bool af32 = (ws_size >= 256 + hBytes + aggF32B);
    const size_t aggBytes = af32 ? aggF32B : aggBf16B;
    k_input<<<(N * H + 255) / 256, 256, 0, stream>>>(x, w_in, b_in, hA2, flag, N);
    for (int i = 0; i < L; ++i) {
      long oW = (long)i * H * H, oU = (long)i * 2 * H * H, oB = (long)i * H;
      hipMemsetAsync(agg2, 0, aggBytes, stream);
      if (af32) {
        k_msg<true><<<(E + 63) / 64, 256, 0, stream>>>(hA2, srcI, dstI,
            msg_w1, msg_b1, msg_w2, msg_b2, oW, oB, agg2, flag, E);
        k_upd<true><<<(N + 63) / 64, 256, 0, stream>>>(hA2, agg2,
            upd_w1, upd_b1, upd_w2, upd_b2, bn_g, bn_b, bn_m, bn_v,
            oU, oW, oB, hA2, flag, N);
      } else {
        k_msg<false><<<(E + 63) / 64, 256, 0, stream>>>(hA2, srcI, dstI,
            msg_w1, msg_b1, msg_w2, msg_b2, oW, oB, agg2, flag, E);
        k_upd<false><<<(N + 63) / 64, 256, 0, stream>>>(hA2, agg2,
            upd_w1, upd_b1, upd_w2, upd_b2, bn_g, bn_b, bn_m, bn_v,
            oU, oW, oB, hA2, flag, N);
      }
    }
    k_out<<<(out_size + 255) / 256, 256, 0, stream>>>(hA2,
        out_w1, out_b1, out_w2, out_b2, d_out, flag, out_size);
  }
}

// Round 9
// 916.360 us; speedup vs baseline: 1.9375x; 1.1071x over previous
//
#include <hip/hip_runtime.h>
#include <hip/hip_bf16.h>

#define H 64
#define PADW 88    // bf16 plane stride (shorts)
#define PADU 136   // bf16 plane stride K=128 (shorts)
#define PADT 68    // f32 transpose-buffer stride (floats)

typedef __attribute__((ext_vector_type(8))) short short8;
typedef __attribute__((ext_vector_type(4))) short short4v;
typedef __attribute__((ext_vector_type(4))) float floatx4;

#define MFMA(a, b, c) __builtin_amdgcn_mfma_f32_16x16x32_bf16(a, b, c, 0, 0, 0)

__device__ __forceinline__ float bf2f(short s) {
  union { unsigned int u; float f; } v;
  v.u = ((unsigned int)(unsigned short)s) << 16;
  return v.f;
}
__device__ __forceinline__ short f2bf(float f) {
  union { float f; unsigned int u; } v; v.f = f;
  unsigned int r = v.u + 0x7fffu + ((v.u >> 16) & 1u);  // RNE
  return (short)(r >> 16);
}
__device__ __forceinline__ void split2(float v, short& hi, short& lo) {
  hi = f2bf(v);
  lo = f2bf(v - bf2f(hi));
}
__device__ __forceinline__ float ldf(const void* p, long idx, bool isf32) {
  return isf32 ? ((const float*)p)[idx] : bf2f(((const short*)p)[idx]);
}

// dtype probe
__global__ void k_probe(const short* __restrict__ x, int* __restrict__ flag) {
  __shared__ int cnt;
  if (threadIdx.x == 0) cnt = 0;
  __syncthreads();
  short s = x[threadIdx.x];
  int e = (s >> 7) & 0xFF;
  int insane = (e != 0 && (e < 100 || e > 140)) ? 1 : 0;
  atomicAdd(&cnt, insane);
  __syncthreads();
  if (threadIdx.x == 0) *flag = (cnt > 64) ? 1 : 0;  // 1 = f32 inputs
}

// h0 = relu(x @ w_in + b_in) -> hi/lo planes
__global__ void k_input2(const void* __restrict__ x, const void* __restrict__ w,
                         const void* __restrict__ b, short* __restrict__ hhi,
                         short* __restrict__ hlo, const int* __restrict__ flag, int N) {
  bool isf32 = (*flag != 0);
  int idx = blockIdx.x * 256 + threadIdx.x;
  if (idx >= N * H) return;
  int v = idx >> 6, k = idx & 63;
  float acc = ldf(b, k, isf32);
#pragma unroll
  for (int d = 0; d < 3; ++d)
    acc += ldf(x, (long)v * 3 + d, isf32) * ldf(w, d * 64 + k, isf32);
  float r = fmaxf(acc, 0.f);
  short hi, lo; split2(r, hi, lo);
  hhi[idx] = hi; hlo[idx] = lo;
}

// ---------------- CSR build, XCD-partitioned (counting sort by dst) ----------------
// blocks with blockIdx%8==x handle dst in [N*x/8, N*(x+1)/8): filtered writes stay
// (heuristically) XCD-local so lines coalesce in that XCD's L2.

__global__ void k_hist_x(const int* __restrict__ dstI, int* __restrict__ deg,
                         int E, int N) {
  const int xcd = blockIdx.x & 7;
  const int grp = blockIdx.x >> 3;
  const int ngrp = gridDim.x >> 3;
  const int lo = (int)(((long)N * xcd) >> 3);
  const int hi = (int)(((long)N * (xcd + 1)) >> 3);
  for (int e = grp * 256 + threadIdx.x; e < E; e += ngrp * 256) {
    int d = dstI[e];
    if (d >= lo && d < hi) atomicAdd(&deg[d], 1);
  }
}

__global__ void k_scan_local(const int* __restrict__ deg, int* __restrict__ rowptr,
                             int* __restrict__ bsum, int N) {
  __shared__ int s[256];
  int tid = threadIdx.x;
  int base = blockIdx.x * 1024 + tid * 4;
  int v0 = (base + 0 < N) ? deg[base + 0] : 0;
  int v1 = (base + 1 < N) ? deg[base + 1] : 0;
  int v2 = (base + 2 < N) ? deg[base + 2] : 0;
  int v3 = (base + 3 < N) ? deg[base + 3] : 0;
  int tsum = v0 + v1 + v2 + v3;
  s[tid] = tsum;
  __syncthreads();
  for (int off = 1; off < 256; off <<= 1) {
    int x = (tid >= off) ? s[tid - off] : 0;
    __syncthreads();
    s[tid] += x;
    __syncthreads();
  }
  int excl = s[tid] - tsum;
  if (base + 0 < N) rowptr[base + 0] = excl;
  if (base + 1 < N) rowptr[base + 1] = excl + v0;
  if (base + 2 < N) rowptr[base + 2] = excl + v0 + v1;
  if (base + 3 < N) rowptr[base + 3] = excl + v0 + v1 + v2;
  if (tid == 255) bsum[blockIdx.x] = s[255];
}

__global__ void k_scan_block(const int* __restrict__ bsum, int* __restrict__ bexcl, int nb) {
  __shared__ int s[256];
  int tid = threadIdx.x;
  int v = (tid < nb) ? bsum[tid] : 0;
  s[tid] = v;
  __syncthreads();
  for (int off = 1; off < 256; off <<= 1) {
    int x = (tid >= off) ? s[tid - off] : 0;
    __syncthreads();
    s[tid] += x;
    __syncthreads();
  }
  bexcl[tid] = s[tid] - v;
}

__global__ void k_scan_add(int* __restrict__ rowptr, int* __restrict__ cursor,
                           const int* __restrict__ bexcl, int N, int E) {
  int i = blockIdx.x * 256 + threadIdx.x;
  if (i < N) {
    int v = rowptr[i] + bexcl[i >> 10];
    rowptr[i] = v;
    cursor[i] = v;
  }
  if (i == N) rowptr[N] = E;
}

__global__ void k_scatter_x(const int* __restrict__ srcI, const int* __restrict__ dstI,
                            int* __restrict__ cursor, int* __restrict__ srcS,
                            int E, int N) {
  const int xcd = blockIdx.x & 7;
  const int grp = blockIdx.x >> 3;
  const int ngrp = gridDim.x >> 3;
  const int lo = (int)(((long)N * xcd) >> 3);
  const int hi = (int)(((long)N * (xcd + 1)) >> 3);
  for (int e = grp * 256 + threadIdx.x; e < E; e += ngrp * 256) {
    int d = dstI[e];
    if (d >= lo && d < hi) {
      int p = atomicAdd(&cursor[d], 1);
      srcS[p] = srcI[e];
    }
  }
}

// ---------------- dense per-node message MLP (layer 0 only) ----------------
__global__ __launch_bounds__(256) void k_mlp(
    const short* __restrict__ hhi, const short* __restrict__ hlo,
    const void* __restrict__ W1, const void* __restrict__ B1,
    const void* __restrict__ W2, long oW, long oB,
    short* __restrict__ M, const int* __restrict__ flag, int N) {
  __shared__ short w1hi[64 * PADW], w1lo[64 * PADW];
  __shared__ short w2hi[64 * PADW], w2lo[64 * PADW];
  __shared__ float b1s[64];
  __shared__ float tbuf[4][16 * PADT];

  bool isf32 = (*flag != 0);
  int tid = threadIdx.x;
  for (int idx = tid; idx < 4096; idx += 256) {
    int j = idx >> 6, k = idx & 63;
    short hi, lo;
    split2(ldf(W1, oW + idx, isf32), hi, lo);
    w1hi[k * PADW + j] = hi; w1lo[k * PADW + j] = lo;
    split2(ldf(W2, oW + idx, isf32), hi, lo);
    w2hi[k * PADW + j] = hi; w2lo[k * PADW + j] = lo;
  }
  if (tid < 64) b1s[tid] = ldf(B1, oB + tid, isf32);
  __syncthreads();

  const int wave = tid >> 6, lane = tid & 63;
  const int m = lane & 15, quad = lane >> 4;
  const int nBase = (blockIdx.x * 4 + wave) * 16;
  int node = nBase + m;
  int nc = node < N ? node : N - 1;

  short8 fhi[2], flo[2];
  fhi[0] = *(const short8*)(hhi + (long)nc * H + quad * 8);
  fhi[1] = *(const short8*)(hhi + (long)nc * H + 32 + quad * 8);
  flo[0] = *(const short8*)(hlo + (long)nc * H + quad * 8);
  flo[1] = *(const short8*)(hlo + (long)nc * H + 32 + quad * 8);

  floatx4 acc[4];
#pragma unroll
  for (int t = 0; t < 4; ++t) acc[t] = (floatx4){0.f, 0.f, 0.f, 0.f};
#pragma unroll
  for (int t = 0; t < 4; ++t) {
    const short* whi = &w1hi[(t * 16 + m) * PADW + quad * 8];
    const short* wlo = &w1lo[(t * 16 + m) * PADW + quad * 8];
    acc[t] = MFMA(fhi[0], *(const short8*)(whi), acc[t]);
    acc[t] = MFMA(fhi[1], *(const short8*)(whi + 32), acc[t]);
    acc[t] = MFMA(flo[0], *(const short8*)(whi), acc[t]);
    acc[t] = MFMA(flo[1], *(const short8*)(whi + 32), acc[t]);
    acc[t] = MFMA(fhi[0], *(const short8*)(wlo), acc[t]);
    acc[t] = MFMA(fhi[1], *(const short8*)(wlo + 32), acc[t]);
  }

  float* tb = tbuf[wave];
#pragma unroll
  for (int t = 0; t < 4; ++t) {
    int col = t * 16 + m;
    float bb = b1s[col];
#pragma unroll
    for (int r = 0; r < 4; ++r)
      tb[(quad * 4 + r) * PADT + col] = fmaxf(acc[t][r] + bb, 0.f);
  }
  __syncthreads();

  float av[16];
  *(floatx4*)(av + 0)  = *(const floatx4*)(&tb[m * PADT + quad * 8]);
  *(floatx4*)(av + 4)  = *(const floatx4*)(&tb[m * PADT + quad * 8 + 4]);
  *(floatx4*)(av + 8)  = *(const floatx4*)(&tb[m * PADT + 32 + quad * 8]);
  *(floatx4*)(av + 12) = *(const floatx4*)(&tb[m * PADT + 32 + quad * 8 + 4]);
  short8 thi0, tlo0, thi1, tlo1;
#pragma unroll
  for (int j = 0; j < 8; ++j) {
    short hi, lo;
    split2(av[j], hi, lo);     thi0[j] = hi; tlo0[j] = lo;
    split2(av[8 + j], hi, lo); thi1[j] = hi; tlo1[j] = lo;
  }

  floatx4 mac[4];
#pragma unroll
  for (int t = 0; t < 4; ++t) mac[t] = (floatx4){0.f, 0.f, 0.f, 0.f};
#pragma unroll
  for (int t = 0; t < 4; ++t) {
    const short* whi = &w2hi[(t * 16 + m) * PADW + quad * 8];
    const short* wlo = &w2lo[(t * 16 + m) * PADW + quad * 8];
    mac[t] = MFMA(thi0, *(const short8*)(whi), mac[t]);
    mac[t] = MFMA(thi1, *(const short8*)(whi + 32), mac[t]);
    mac[t] = MFMA(tlo0, *(const short8*)(whi), mac[t]);
    mac[t] = MFMA(tlo1, *(const short8*)(whi + 32), mac[t]);
    mac[t] = MFMA(thi0, *(const short8*)(wlo), mac[t]);
    mac[t] = MFMA(thi1, *(const short8*)(wlo + 32), mac[t]);
  }

#pragma unroll
  for (int t = 0; t < 4; ++t) {
    int col = t * 16 + m;
#pragma unroll
    for (int r = 0; r < 4; ++r) {
      int nrow = nBase + quad * 4 + r;
      if (nrow < N) M[(long)nrow * H + col] = f2bf(mac[t][r]);
    }
  }
}

// ---------------- gather-sum: agg[d] = sum_seg M[src] + deg*b2 ----------------
__global__ __launch_bounds__(256) void k_gather(
    const short* __restrict__ M, const int* __restrict__ rowptr,
    const int* __restrict__ srcS, const void* __restrict__ B2, long oB,
    short* __restrict__ agg, const int* __restrict__ flag, int N, int totWaves) {
  __shared__ float b2s[64];
  bool isf32 = (*flag != 0);
  if (threadIdx.x < 64) b2s[threadIdx.x] = ldf(B2, oB + threadIdx.x, isf32);
  __syncthreads();
  const int wave = threadIdx.x >> 6, lane = threadIdx.x & 63;
  const int g = lane >> 4, l = lane & 15;
  float b2v[4];
#pragma unroll
  for (int j = 0; j < 4; ++j) b2v[j] = b2s[l * 4 + j];

  const int gw = blockIdx.x * 4 + wave;
  const int nTask = (N + 3) >> 2;
  for (int task = gw; task < nTask; task += totWaves) {
    int n = task * 4 + g;
    bool valid = n < N;
    int nc = valid ? n : N - 1;
    int rs = rowptr[nc], re = rowptr[nc + 1];
    if (!valid) { rs = 0; re = 0; }
    float a0 = 0.f, a1 = 0.f, a2 = 0.f, a3 = 0.f;
    for (int e = rs; e < re; e += 4) {
      int c1 = e + 1 < re ? e + 1 : re - 1;
      int c2 = e + 2 < re ? e + 2 : re - 1;
      int c3 = e + 3 < re ? e + 3 : re - 1;
      int s0 = srcS[e], s1 = srcS[c1], s2 = srcS[c2], s3 = srcS[c3];
      short4v r0 = *(const short4v*)(M + (long)s0 * H + l * 4);
      short4v r1 = *(const short4v*)(M + (long)s1 * H + l * 4);
      short4v r2 = *(const short4v*)(M + (long)s2 * H + l * 4);
      short4v r3 = *(const short4v*)(M + (long)s3 * H + l * 4);
      a0 += bf2f(r0[0]); a1 += bf2f(r0[1]); a2 += bf2f(r0[2]); a3 += bf2f(r0[3]);
      if (e + 1 < re) { a0 += bf2f(r1[0]); a1 += bf2f(r1[1]); a2 += bf2f(r1[2]); a3 += bf2f(r1[3]); }
      if (e + 2 < re) { a0 += bf2f(r2[0]); a1 += bf2f(r2[1]); a2 += bf2f(r2[2]); a3 += bf2f(r2[3]); }
      if (e + 3 < re) { a0 += bf2f(r3[0]); a1 += bf2f(r3[1]); a2 += bf2f(r3[2]); a3 += bf2f(r3[3]); }
    }
    if (valid) {
      float dv = (float)(re - rs);
      short4v o;
      o[0] = f2bf(a0 + dv * b2v[0]);
      o[1] = f2bf(a1 + dv * b2v[1]);
      o[2] = f2bf(a2 + dv * b2v[2]);
      o[3] = f2bf(a3 + dv * b2v[3]);
      *(short4v*)(agg + (long)n * H + l * 4) = o;
    }
  }
}

// ---------------- fused update + next-layer message MLP ----------------
// h_{i+1} = relu(BN(relu([h|agg]@U1+ub1)@U2+ub2) + h); then (if doMsg)
// M = relu(h_{i+1}@W1m+mb1)@W2m. All weights hi-only bf16 (LDS ~68KB, 2 blk/CU);
// h activations keep hi+lo. In-place safe (block-disjoint node rows).
__global__ __launch_bounds__(256) void k_updm(
    short* __restrict__ hhi, short* __restrict__ hlo, const short* __restrict__ agg,
    const void* __restrict__ U1, const void* __restrict__ UB1,
    const void* __restrict__ U2, const void* __restrict__ UB2,
    const void* __restrict__ G, const void* __restrict__ Bb,
    const void* __restrict__ Mm, const void* __restrict__ Vv,
    const void* __restrict__ W1m, const void* __restrict__ B1m,
    const void* __restrict__ W2m,
    long oU, long oW, long oB, long oWn, long oBn,
    short* __restrict__ Mout, const int* __restrict__ flag, int N, int doMsg) {
  __shared__ short u1h[64 * PADU];
  __shared__ short u2h[64 * PADW];
  __shared__ short m1h[64 * PADW];
  __shared__ short m2h[64 * PADW];
  __shared__ float b1s[64], b2s[64], scl[64], sft[64], mb1[64];
  __shared__ float tbuf[4][16 * PADT];

  bool isf32 = (*flag != 0);
  int tid = threadIdx.x;
  for (int idx = tid; idx < 8192; idx += 256) {
    int j = idx >> 6, k = idx & 63;
    u1h[k * PADU + j] = f2bf(ldf(U1, oU + idx, isf32));
  }
  for (int idx = tid; idx < 4096; idx += 256) {
    int j = idx >> 6, k = idx & 63;
    u2h[k * PADW + j] = f2bf(ldf(U2, oW + idx, isf32));
    m1h[k * PADW + j] = f2bf(ldf(W1m, oWn + idx, isf32));
    m2h[k * PADW + j] = f2bf(ldf(W2m, oWn + idx, isf32));
  }
  if (tid < 64) {
    b1s[tid] = ldf(UB1, oB + tid, isf32);
    b2s[tid] = ldf(UB2, oB + tid, isf32);
    float s = ldf(G, oB + tid, isf32) * rsqrtf(ldf(Vv, oB + tid, isf32) + 1e-5f);
    scl[tid] = s;
    sft[tid] = ldf(Bb, oB + tid, isf32) - ldf(Mm, oB + tid, isf32) * s;
    mb1[tid] = ldf(B1m, oBn + tid, isf32);
  }
  __syncthreads();

  const int wave = tid >> 6, lane = tid & 63;
  const int m = lane & 15, quad = lane >> 4;
  const int nBase = (blockIdx.x * 4 + wave) * 16;
  int node = nBase + m;
  int nc = node < N ? node : N - 1;
  float* tb = tbuf[wave];

  // A-frags: [h(hi,lo) | agg(hi)]
  short8 fhi[4], flo[2];
  fhi[0] = *(const short8*)(hhi + (long)nc * H + quad * 8);
  fhi[1] = *(const short8*)(hhi + (long)nc * H + 32 + quad * 8);
  flo[0] = *(const short8*)(hlo + (long)nc * H + quad * 8);
  flo[1] = *(const short8*)(hlo + (long)nc * H + 32 + quad * 8);
  fhi[2] = *(const short8*)(agg + (long)nc * H + quad * 8);
  fhi[3] = *(const short8*)(agg + (long)nc * H + 32 + quad * 8);

  // upd GEMM1 (K=128, weights hi-only)
  floatx4 acc[4];
#pragma unroll
  for (int t = 0; t < 4; ++t) acc[t] = (floatx4){0.f, 0.f, 0.f, 0.f};
#pragma unroll
  for (int t = 0; t < 4; ++t) {
    const short* wp = &u1h[(t * 16 + m) * PADU + quad * 8];
#pragma unroll
    for (int c = 0; c < 4; ++c) {
      acc[t] = MFMA(fhi[c], *(const short8*)(wp + 32 * c), acc[t]);
      if (c < 2) acc[t] = MFMA(flo[c], *(const short8*)(wp + 32 * c), acc[t]);
    }
  }

  // P -> tbuf -> A-frag
#pragma unroll
  for (int t = 0; t < 4; ++t) {
    int col = t * 16 + m;
    float bb = b1s[col];
#pragma unroll
    for (int r = 0; r < 4; ++r)
      tb[(quad * 4 + r) * PADT + col] = fmaxf(acc[t][r] + bb, 0.f);
  }
  __syncthreads();
  float av[16];
  *(floatx4*)(av + 0)  = *(const floatx4*)(&tb[m * PADT + quad * 8]);
  *(floatx4*)(av + 4)  = *(const floatx4*)(&tb[m * PADT + quad * 8 + 4]);
  *(floatx4*)(av + 8)  = *(const floatx4*)(&tb[m * PADT + 32 + quad * 8]);
  *(floatx4*)(av + 12) = *(const floatx4*)(&tb[m * PADT + 32 + quad * 8 + 4]);
  short8 thi[2], tlo[2];
#pragma unroll
  for (int j = 0; j < 8; ++j) {
    short hi, lo;
    split2(av[j], hi, lo);     thi[0][j] = hi; tlo[0][j] = lo;
    split2(av[8 + j], hi, lo); thi[1][j] = hi; tlo[1][j] = lo;
  }

  // upd GEMM2 (weights hi-only)
  floatx4 mac[4];
#pragma unroll
  for (int t = 0; t < 4; ++t) mac[t] = (floatx4){0.f, 0.f, 0.f, 0.f};
#pragma unroll
  for (int t = 0; t < 4; ++t) {
    const short* wp = &u2h[(t * 16 + m) * PADW + quad * 8];
#pragma unroll
    for (int c = 0; c < 2; ++c) {
      mac[t] = MFMA(thi[c], *(const short8*)(wp + 32 * c), mac[t]);
      mac[t] = MFMA(tlo[c], *(const short8*)(wp + 32 * c), mac[t]);
    }
  }

  // epilogue: BN + residual relu; write h planes; also deposit h_new into tbuf
  __syncthreads();  // tbuf reads above complete before rewrite
#pragma unroll
  for (int t = 0; t < 4; ++t) {
    int col = t * 16 + m;
    float bb = b2s[col], ss = scl[col], ff = sft[col];
#pragma unroll
    for (int r = 0; r < 4; ++r) {
      int nrow = nBase + quad * 4 + r;
      float hn = 0.f;
      if (nrow < N) {
        long el = (long)nrow * H + col;
        float hv = (mac[t][r] + bb) * ss + ff;
        float ho = bf2f(hhi[el]) + bf2f(hlo[el]);
        hn = fmaxf(hv + ho, 0.f);
        short hi2, lo2; split2(hn, hi2, lo2);
        hhi[el] = hi2; hlo[el] = lo2;
      }
      tb[(quad * 4 + r) * PADT + col] = hn;
    }
  }

  if (doMsg) {
    // h_new A-frag from tbuf
    __syncthreads();
    *(floatx4*)(av + 0)  = *(const floatx4*)(&tb[m * PADT + quad * 8]);
    *(floatx4*)(av + 4)  = *(const floatx4*)(&tb[m * PADT + quad * 8 + 4]);
    *(floatx4*)(av + 8)  = *(const floatx4*)(&tb[m * PADT + 32 + quad * 8]);
    *(floatx4*)(av + 12) = *(const floatx4*)(&tb[m * PADT + 32 + quad * 8 + 4]);
#pragma unroll
    for (int j = 0; j < 8; ++j) {
      short hi, lo;
      split2(av[j], hi, lo);     thi[0][j] = hi; tlo[0][j] = lo;
      split2(av[8 + j], hi, lo); thi[1][j] = hi; tlo[1][j] = lo;
    }

    // msg GEMM1 (weights hi-only, h hi+lo)
#pragma unroll
    for (int t = 0; t < 4; ++t) acc[t] = (floatx4){0.f, 0.f, 0.f, 0.f};
#pragma unroll
    for (int t = 0; t < 4; ++t) {
      const short* wp = &m1h[(t * 16 + m) * PADW + quad * 8];
#pragma unroll
      for (int c = 0; c < 2; ++c) {
        acc[t] = MFMA(thi[c], *(const short8*)(wp + 32 * c), acc[t]);
        acc[t] = MFMA(tlo[c], *(const short8*)(wp + 32 * c), acc[t]);
      }
    }

    __syncthreads();  // tbuf reads complete
#pragma unroll
    for (int t = 0; t < 4; ++t) {
      int col = t * 16 + m;
      float bb = mb1[col];
#pragma unroll
      for (int r = 0; r < 4; ++r)
        tb[(quad * 4 + r) * PADT + col] = fmaxf(acc[t][r] + bb, 0.f);
    }
    __syncthreads();
    *(floatx4*)(av + 0)  = *(const floatx4*)(&tb[m * PADT + quad * 8]);
    *(floatx4*)(av + 4)  = *(const floatx4*)(&tb[m * PADT + quad * 8 + 4]);
    *(floatx4*)(av + 8)  = *(const floatx4*)(&tb[m * PADT + 32 + quad * 8]);
    *(floatx4*)(av + 12) = *(const floatx4*)(&tb[m * PADT + 32 + quad * 8 + 4]);
#pragma unroll
    for (int j = 0; j < 8; ++j) {
      short hi, lo;
      split2(av[j], hi, lo);     thi[0][j] = hi; tlo[0][j] = lo;
      split2(av[8 + j], hi, lo); thi[1][j] = hi; tlo[1][j] = lo;
    }

    // msg GEMM2 (weights hi-only)
#pragma unroll
    for (int t = 0; t < 4; ++t) mac[t] = (floatx4){0.f, 0.f, 0.f, 0.f};
#pragma unroll
    for (int t = 0; t < 4; ++t) {
      const short* wp = &m2h[(t * 16 + m) * PADW + quad * 8];
#pragma unroll
      for (int c = 0; c < 2; ++c) {
        mac[t] = MFMA(thi[c], *(const short8*)(wp + 32 * c), mac[t]);
        mac[t] = MFMA(tlo[c], *(const short8*)(wp + 32 * c), mac[t]);
      }
    }

#pragma unroll
    for (int t = 0; t < 4; ++t) {
      int col = t * 16 + m;
#pragma unroll
      for (int r = 0; r < 4; ++r) {
        int nrow = nBase + quad * 4 + r;
        if (nrow < N) Mout[(long)nrow * H + col] = f2bf(mac[t][r]);
      }
    }
  }
}

// readout from hi/lo planes
__global__ __launch_bounds__(256) void k_out2(
    const short* __restrict__ hhi, const short* __restrict__ hlo,
    const void* __restrict__ W1, const void* __restrict__ B1,
    const void* __restrict__ W2, const void* __restrict__ B2,
    void* __restrict__ out, const int* __restrict__ flag, int NQ) {
  __shared__ float w1s[64 * 32];
  __shared__ float b1sh[32], w2s[32];
  bool isf32 = (*flag != 0);
  int tid = threadIdx.x;
  for (int idx = tid; idx < 2048; idx += 256) w1s[idx] = ldf(W1, idx, isf32);
  if (tid < 32) { b1sh[tid] = ldf(B1, tid, isf32); w2s[tid] = ldf(W2, tid, isf32); }
  __syncthreads();
  int v = blockIdx.x * 256 + tid;
  if (v >= NQ) return;
  float hr[64];
#pragma unroll
  for (int j = 0; j < 64; ++j)
    hr[j] = bf2f(hhi[(long)v * H + j]) + bf2f(hlo[(long)v * H + j]);
  float accum = ldf(B2, 0, isf32);
#pragma unroll 4
  for (int k = 0; k < 32; ++k) {
    float t = b1sh[k];
#pragma unroll
    for (int j = 0; j < 64; ++j) t += hr[j] * w1s[j * 32 + k];
    accum += fmaxf(t, 0.f) * w2s[k];
  }
  if (isf32) ((float*)out)[v] = accum;
  else ((short*)out)[v] = f2bf(accum);
}

extern "C" void kernel_launch(void* const* d_in, const int* in_sizes, int n_in,
                              void* d_out, int out_size, void* d_ws, size_t ws_size,
                              hipStream_t stream) {
  const void* x      = d_in[0];
  const int*  ei     = (const int*)d_in[1];
  const void* w_in   = d_in[3];
  const void* b_in   = d_in[4];
  const void* msg_w1 = d_in[5];
  const void* msg_b1 = d_in[6];
  const void* msg_w2 = d_in[7];
  const void* msg_b2 = d_in[8];
  const void* upd_w1 = d_in[9];
  const void* upd_b1 = d_in[10];
  const void* upd_w2 = d_in[11];
  const void* upd_b2 = d_in[12];
  const void* bn_g   = d_in[13];
  const void* bn_b   = d_in[14];
  const void* bn_m   = d_in[15];
  const void* bn_v   = d_in[16];
  const void* out_w1 = d_in[17];
  const void* out_b1 = d_in[18];
  const void* out_w2 = d_in[19];
  const void* out_b2 = d_in[20];

  const int N = in_sizes[0] / 3;
  const int E = in_sizes[1] / 2;
  const int L = in_sizes[5] / (H * H);
  const int* srcI = ei;
  const int* dstI = ei + E;

  // workspace layout (256B-aligned slots)
  size_t off = 0;
  auto alloc = [&](size_t bytes) { size_t o = off; off += (bytes + 255) & ~(size_t)255; return o; };
  size_t o_flag   = alloc(256);
  size_t o_hhi    = alloc((size_t)N * H * sizeof(short));
  size_t o_hlo    = alloc((size_t)N * H * sizeof(short));
  size_t o_agg    = alloc((size_t)N * H * sizeof(short));
  size_t o_M      = alloc((size_t)N * H * sizeof(short));
  size_t o_rowptr = alloc((size_t)(N + 1) * sizeof(int));
  size_t o_cursor = alloc((size_t)N * sizeof(int));
  size_t o_bsum   = alloc(256 * sizeof(int));
  size_t o_bexcl  = alloc(256 * sizeof(int));
  size_t o_srcS   = alloc((size_t)E * sizeof(int));
  const int NB = (N + 1023) >> 10;

  char* ws = (char*)d_ws;
  int*   flag   = (int*)(ws + o_flag);
  short* hhi    = (short*)(ws + o_hhi);
  short* hlo    = (short*)(ws + o_hlo);
  short* aggS   = (short*)(ws + o_agg);
  short* Mbuf   = (short*)(ws + o_M);
  int*   rowptr = (int*)(ws + o_rowptr);
  int*   deg    = (int*)(ws + o_cursor);
  int*   bsum   = (int*)(ws + o_bsum);
  int*   bexcl  = (int*)(ws + o_bexcl);
  int*   srcS   = (int*)(ws + o_srcS);

  k_probe<<<1, 256, 0, stream>>>((const short*)x, flag);
  k_input2<<<(N * H + 255) / 256, 256, 0, stream>>>(x, w_in, b_in, hhi, hlo, flag, N);

  // CSR build, XCD-partitioned
  hipMemsetAsync(deg, 0, (size_t)N * sizeof(int), stream);
  k_hist_x<<<8 * 128, 256, 0, stream>>>(dstI, deg, E, N);
  k_scan_local<<<NB, 256, 0, stream>>>(deg, rowptr, bsum, N);
  k_scan_block<<<1, 256, 0, stream>>>(bsum, bexcl, NB);
  k_scan_add<<<(N + 256) / 256, 256, 0, stream>>>(rowptr, deg, bexcl, N, E);
  k_scatter_x<<<8 * 128, 256, 0, stream>>>(srcI, dstI, deg, srcS, E, N);

  // M_0 (full-precision standalone MLP)
  k_mlp<<<(N + 63) / 64, 256, 0, stream>>>(hhi, hlo,
      msg_w1, msg_b1, msg_w2, 0, 0, Mbuf, flag, N);

  const int GB = 2048;
  for (int i = 0; i < L; ++i) {
    long oW = (long)i * H * H, oU = (long)i * 2 * H * H, oB = (long)i * H;
    int doMsg = (i + 1 < L) ? 1 : 0;
    long oWn = doMsg ? (long)(i + 1) * H * H : 0;
    long oBn = doMsg ? (long)(i + 1) * H : 0;
    k_gather<<<GB, 256, 0, stream>>>(Mbuf, rowptr, srcS,
        msg_b2, oB, aggS, flag, N, GB * 4);
    k_updm<<<(N + 63) / 64, 256, 0, stream>>>(hhi, hlo, aggS,
        upd_w1, upd_b1, upd_w2, upd_b2, bn_g, bn_b, bn_m, bn_v,
        msg_w1, msg_b1, msg_w2,
        oU, oW, oB, oWn, oBn, Mbuf, flag, N, doMsg);
  }
  k_out2<<<(out_size + 255) / 256, 256, 0, stream>>>(hhi, hlo,
      out_w1, out_b1, out_w2, out_b2, d_out, flag, out_size);
}

// Round 10
// 728.590 us; speedup vs baseline: 2.4368x; 1.2577x over previous
//
#include <hip/hip_runtime.h>
#include <hip/hip_bf16.h>

#define H 64
#define PADW 88    // bf16 plane stride (shorts)
#define PADU 136   // bf16 plane stride K=128 (shorts)
#define PADT 68    // f32 transpose-buffer stride (floats)

typedef __attribute__((ext_vector_type(8))) short short8;
typedef __attribute__((ext_vector_type(4))) short short4v;
typedef __attribute__((ext_vector_type(4))) float floatx4;

#define MFMA(a, b, c) __builtin_amdgcn_mfma_f32_16x16x32_bf16(a, b, c, 0, 0, 0)

__device__ __forceinline__ float bf2f(short s) {
  union { unsigned int u; float f; } v;
  v.u = ((unsigned int)(unsigned short)s) << 16;
  return v.f;
}
__device__ __forceinline__ short f2bf(float f) {
  union { float f; unsigned int u; } v; v.f = f;
  unsigned int r = v.u + 0x7fffu + ((v.u >> 16) & 1u);  // RNE
  return (short)(r >> 16);
}
__device__ __forceinline__ void split2(float v, short& hi, short& lo) {
  hi = f2bf(v);
  lo = f2bf(v - bf2f(hi));
}
__device__ __forceinline__ float ldf(const void* p, long idx, bool isf32) {
  return isf32 ? ((const float*)p)[idx] : bf2f(((const short*)p)[idx]);
}

// dtype probe
__global__ void k_probe(const short* __restrict__ x, int* __restrict__ flag) {
  __shared__ int cnt;
  if (threadIdx.x == 0) cnt = 0;
  __syncthreads();
  short s = x[threadIdx.x];
  int e = (s >> 7) & 0xFF;
  int insane = (e != 0 && (e < 100 || e > 140)) ? 1 : 0;
  atomicAdd(&cnt, insane);
  __syncthreads();
  if (threadIdx.x == 0) *flag = (cnt > 64) ? 1 : 0;  // 1 = f32 inputs
}

// h0 = relu(x @ w_in + b_in) -> hi/lo planes
__global__ void k_input2(const void* __restrict__ x, const void* __restrict__ w,
                         const void* __restrict__ b, short* __restrict__ hhi,
                         short* __restrict__ hlo, const int* __restrict__ flag, int N) {
  bool isf32 = (*flag != 0);
  int idx = blockIdx.x * 256 + threadIdx.x;
  if (idx >= N * H) return;
  int v = idx >> 6, k = idx & 63;
  float acc = ldf(b, k, isf32);
#pragma unroll
  for (int d = 0; d < 3; ++d)
    acc += ldf(x, (long)v * 3 + d, isf32) * ldf(w, d * 64 + k, isf32);
  float r = fmaxf(acc, 0.f);
  short hi, lo; split2(r, hi, lo);
  hhi[idx] = hi; hlo[idx] = lo;
}

// ---------------- CSR build, XCD-partitioned (counting sort by dst) ----------------

__global__ void k_hist_x(const int* __restrict__ dstI, int* __restrict__ deg,
                         int E, int N) {
  const int xcd = blockIdx.x & 7;
  const int grp = blockIdx.x >> 3;
  const int ngrp = gridDim.x >> 3;
  const int lo = (int)(((long)N * xcd) >> 3);
  const int hi = (int)(((long)N * (xcd + 1)) >> 3);
  for (int e = grp * 256 + threadIdx.x; e < E; e += ngrp * 256) {
    int d = dstI[e];
    if (d >= lo && d < hi) atomicAdd(&deg[d], 1);
  }
}

__global__ void k_scan_local(const int* __restrict__ deg, int* __restrict__ rowptr,
                             int* __restrict__ bsum, int N) {
  __shared__ int s[256];
  int tid = threadIdx.x;
  int base = blockIdx.x * 1024 + tid * 4;
  int v0 = (base + 0 < N) ? deg[base + 0] : 0;
  int v1 = (base + 1 < N) ? deg[base + 1] : 0;
  int v2 = (base + 2 < N) ? deg[base + 2] : 0;
  int v3 = (base + 3 < N) ? deg[base + 3] : 0;
  int tsum = v0 + v1 + v2 + v3;
  s[tid] = tsum;
  __syncthreads();
  for (int off = 1; off < 256; off <<= 1) {
    int x = (tid >= off) ? s[tid - off] : 0;
    __syncthreads();
    s[tid] += x;
    __syncthreads();
  }
  int excl = s[tid] - tsum;
  if (base + 0 < N) rowptr[base + 0] = excl;
  if (base + 1 < N) rowptr[base + 1] = excl + v0;
  if (base + 2 < N) rowptr[base + 2] = excl + v0 + v1;
  if (base + 3 < N) rowptr[base + 3] = excl + v0 + v1 + v2;
  if (tid == 255) bsum[blockIdx.x] = s[255];
}

__global__ void k_scan_block(const int* __restrict__ bsum, int* __restrict__ bexcl, int nb) {
  __shared__ int s[256];
  int tid = threadIdx.x;
  int v = (tid < nb) ? bsum[tid] : 0;
  s[tid] = v;
  __syncthreads();
  for (int off = 1; off < 256; off <<= 1) {
    int x = (tid >= off) ? s[tid - off] : 0;
    __syncthreads();
    s[tid] += x;
    __syncthreads();
  }
  bexcl[tid] = s[tid] - v;
}

__global__ void k_scan_add(int* __restrict__ rowptr, int* __restrict__ cursor,
                           const int* __restrict__ bexcl, int N, int E) {
  int i = blockIdx.x * 256 + threadIdx.x;
  if (i < N) {
    int v = rowptr[i] + bexcl[i >> 10];
    rowptr[i] = v;
    cursor[i] = v;
  }
  if (i == N) rowptr[N] = E;
}

__global__ void k_scatter_x(const int* __restrict__ srcI, const int* __restrict__ dstI,
                            int* __restrict__ cursor, int* __restrict__ srcS,
                            int E, int N) {
  const int xcd = blockIdx.x & 7;
  const int grp = blockIdx.x >> 3;
  const int ngrp = gridDim.x >> 3;
  const int lo = (int)(((long)N * xcd) >> 3);
  const int hi = (int)(((long)N * (xcd + 1)) >> 3);
  for (int e = grp * 256 + threadIdx.x; e < E; e += ngrp * 256) {
    int d = dstI[e];
    if (d >= lo && d < hi) {
      int p = atomicAdd(&cursor[d], 1);
      srcS[p] = srcI[e];
    }
  }
}

// ---------------- dense per-node message MLP (layer 0 only) ----------------
__global__ __launch_bounds__(256) void k_mlp(
    const short* __restrict__ hhi, const short* __restrict__ hlo,
    const void* __restrict__ W1, const void* __restrict__ B1,
    const void* __restrict__ W2, long oW, long oB,
    short* __restrict__ M, const int* __restrict__ flag, int N) {
  __shared__ short w1hi[64 * PADW], w1lo[64 * PADW];
  __shared__ short w2hi[64 * PADW], w2lo[64 * PADW];
  __shared__ float b1s[64];
  __shared__ float tbuf[4][16 * PADT];

  bool isf32 = (*flag != 0);
  int tid = threadIdx.x;
  for (int idx = tid; idx < 4096; idx += 256) {
    int j = idx >> 6, k = idx & 63;
    short hi, lo;
    split2(ldf(W1, oW + idx, isf32), hi, lo);
    w1hi[k * PADW + j] = hi; w1lo[k * PADW + j] = lo;
    split2(ldf(W2, oW + idx, isf32), hi, lo);
    w2hi[k * PADW + j] = hi; w2lo[k * PADW + j] = lo;
  }
  if (tid < 64) b1s[tid] = ldf(B1, oB + tid, isf32);
  __syncthreads();

  const int wave = tid >> 6, lane = tid & 63;
  const int m = lane & 15, quad = lane >> 4;
  float* tb = tbuf[wave];

  for (int nb = blockIdx.x * 64; nb < N; nb += gridDim.x * 64) {
    const int nBase = nb + wave * 16;
    int node = nBase + m;
    int nc = node < N ? node : N - 1;

    short8 fhi[2], flo[2];
    fhi[0] = *(const short8*)(hhi + (long)nc * H + quad * 8);
    fhi[1] = *(const short8*)(hhi + (long)nc * H + 32 + quad * 8);
    flo[0] = *(const short8*)(hlo + (long)nc * H + quad * 8);
    flo[1] = *(const short8*)(hlo + (long)nc * H + 32 + quad * 8);

    floatx4 acc[4];
#pragma unroll
    for (int t = 0; t < 4; ++t) acc[t] = (floatx4){0.f, 0.f, 0.f, 0.f};
#pragma unroll
    for (int t = 0; t < 4; ++t) {
      const short* whi = &w1hi[(t * 16 + m) * PADW + quad * 8];
      const short* wlo = &w1lo[(t * 16 + m) * PADW + quad * 8];
      acc[t] = MFMA(fhi[0], *(const short8*)(whi), acc[t]);
      acc[t] = MFMA(fhi[1], *(const short8*)(whi + 32), acc[t]);
      acc[t] = MFMA(flo[0], *(const short8*)(whi), acc[t]);
      acc[t] = MFMA(flo[1], *(const short8*)(whi + 32), acc[t]);
      acc[t] = MFMA(fhi[0], *(const short8*)(wlo), acc[t]);
      acc[t] = MFMA(fhi[1], *(const short8*)(wlo + 32), acc[t]);
    }

#pragma unroll
    for (int t = 0; t < 4; ++t) {
      int col = t * 16 + m;
      float bb = b1s[col];
#pragma unroll
      for (int r = 0; r < 4; ++r)
        tb[(quad * 4 + r) * PADT + col] = fmaxf(acc[t][r] + bb, 0.f);
    }

    float av[16];
    *(floatx4*)(av + 0)  = *(const floatx4*)(&tb[m * PADT + quad * 8]);
    *(floatx4*)(av + 4)  = *(const floatx4*)(&tb[m * PADT + quad * 8 + 4]);
    *(floatx4*)(av + 8)  = *(const floatx4*)(&tb[m * PADT + 32 + quad * 8]);
    *(floatx4*)(av + 12) = *(const floatx4*)(&tb[m * PADT + 32 + quad * 8 + 4]);
    short8 thi0, tlo0, thi1, tlo1;
#pragma unroll
    for (int j = 0; j < 8; ++j) {
      short hi, lo;
      split2(av[j], hi, lo);     thi0[j] = hi; tlo0[j] = lo;
      split2(av[8 + j], hi, lo); thi1[j] = hi; tlo1[j] = lo;
    }

    floatx4 mac[4];
#pragma unroll
    for (int t = 0; t < 4; ++t) mac[t] = (floatx4){0.f, 0.f, 0.f, 0.f};
#pragma unroll
    for (int t = 0; t < 4; ++t) {
      const short* whi = &w2hi[(t * 16 + m) * PADW + quad * 8];
      const short* wlo = &w2lo[(t * 16 + m) * PADW + quad * 8];
      mac[t] = MFMA(thi0, *(const short8*)(whi), mac[t]);
      mac[t] = MFMA(thi1, *(const short8*)(whi + 32), mac[t]);
      mac[t] = MFMA(tlo0, *(const short8*)(whi), mac[t]);
      mac[t] = MFMA(tlo1, *(const short8*)(whi + 32), mac[t]);
      mac[t] = MFMA(thi0, *(const short8*)(wlo), mac[t]);
      mac[t] = MFMA(thi1, *(const short8*)(wlo + 32), mac[t]);
    }

#pragma unroll
    for (int t = 0; t < 4; ++t) {
      int col = t * 16 + m;
#pragma unroll
      for (int r = 0; r < 4; ++r) {
        int nrow = nBase + quad * 4 + r;
        if (nrow < N) M[(long)nrow * H + col] = f2bf(mac[t][r]);
      }
    }
  }
}

// ---------------- gather-sum: agg[d] = sum_seg M[src] + deg*b2 ----------------
// 4 node-streams per wave; 16 lanes cover a 128B bf16 row; 8-edge unroll.
__global__ __launch_bounds__(256) void k_gather(
    const short* __restrict__ M, const int* __restrict__ rowptr,
    const int* __restrict__ srcS, const void* __restrict__ B2, long oB,
    short* __restrict__ agg, const int* __restrict__ flag, int N, int totWaves) {
  __shared__ float b2s[64];
  bool isf32 = (*flag != 0);
  if (threadIdx.x < 64) b2s[threadIdx.x] = ldf(B2, oB + threadIdx.x, isf32);
  __syncthreads();
  const int wave = threadIdx.x >> 6, lane = threadIdx.x & 63;
  const int g = lane >> 4, l = lane & 15;
  float b2v[4];
#pragma unroll
  for (int j = 0; j < 4; ++j) b2v[j] = b2s[l * 4 + j];

  const int gw = blockIdx.x * 4 + wave;
  const int nTask = (N + 3) >> 2;
  for (int task = gw; task < nTask; task += totWaves) {
    int n = task * 4 + g;
    bool valid = n < N;
    int nc = valid ? n : N - 1;
    int rs = rowptr[nc], re = rowptr[nc + 1];
    if (!valid) { rs = 0; re = 0; }
    float a0 = 0.f, a1 = 0.f, a2 = 0.f, a3 = 0.f;
    for (int e = rs; e < re; e += 8) {
      int sv[8];
#pragma unroll
      for (int u = 0; u < 8; ++u) {
        int c = e + u < re ? e + u : re - 1;
        sv[u] = srcS[c];
      }
      short4v rr[8];
#pragma unroll
      for (int u = 0; u < 8; ++u)
        rr[u] = *(const short4v*)(M + (long)sv[u] * H + l * 4);
#pragma unroll
      for (int u = 0; u < 8; ++u) {
        if (e + u < re) {
          a0 += bf2f(rr[u][0]); a1 += bf2f(rr[u][1]);
          a2 += bf2f(rr[u][2]); a3 += bf2f(rr[u][3]);
        }
      }
    }
    if (valid) {
      float dv = (float)(re - rs);
      short4v o;
      o[0] = f2bf(a0 + dv * b2v[0]);
      o[1] = f2bf(a1 + dv * b2v[1]);
      o[2] = f2bf(a2 + dv * b2v[2]);
      o[3] = f2bf(a3 + dv * b2v[3]);
      *(short4v*)(agg + (long)n * H + l * 4) = o;
    }
  }
}

// ---------------- persistent fused update + next-layer message MLP ----------------
// Weights staged ONCE per block; grid-stride over 64-node batches. tbuf is
// per-wave scratch -> no intra-batch __syncthreads (wave-order + lgkmcnt
// suffice for own-wave LDS write->read). In-place safe: each node row is
// processed by exactly one wave.
__global__ __launch_bounds__(256) void k_updm(
    short* __restrict__ hhi, short* __restrict__ hlo, const short* __restrict__ agg,
    const void* __restrict__ U1, const void* __restrict__ UB1,
    const void* __restrict__ U2, const void* __restrict__ UB2,
    const void* __restrict__ G, const void* __restrict__ Bb,
    const void* __restrict__ Mm, const void* __restrict__ Vv,
    const void* __restrict__ W1m, const void* __restrict__ B1m,
    const void* __restrict__ W2m,
    long oU, long oW, long oB, long oWn, long oBn,
    short* __restrict__ Mout, const int* __restrict__ flag, int N, int doMsg) {
  __shared__ short u1h[64 * PADU];
  __shared__ short u2h[64 * PADW];
  __shared__ short m1h[64 * PADW];
  __shared__ short m2h[64 * PADW];
  __shared__ float b1s[64], b2s[64], scl[64], sft[64], mb1[64];
  __shared__ float tbuf[4][16 * PADT];

  bool isf32 = (*flag != 0);
  int tid = threadIdx.x;
  for (int idx = tid; idx < 8192; idx += 256) {
    int j = idx >> 6, k = idx & 63;
    u1h[k * PADU + j] = f2bf(ldf(U1, oU + idx, isf32));
  }
  for (int idx = tid; idx < 4096; idx += 256) {
    int j = idx >> 6, k = idx & 63;
    u2h[k * PADW + j] = f2bf(ldf(U2, oW + idx, isf32));
    m1h[k * PADW + j] = f2bf(ldf(W1m, oWn + idx, isf32));
    m2h[k * PADW + j] = f2bf(ldf(W2m, oWn + idx, isf32));
  }
  if (tid < 64) {
    b1s[tid] = ldf(UB1, oB + tid, isf32);
    b2s[tid] = ldf(UB2, oB + tid, isf32);
    float s = ldf(G, oB + tid, isf32) * rsqrtf(ldf(Vv, oB + tid, isf32) + 1e-5f);
    scl[tid] = s;
    sft[tid] = ldf(Bb, oB + tid, isf32) - ldf(Mm, oB + tid, isf32) * s;
    mb1[tid] = ldf(B1m, oBn + tid, isf32);
  }
  __syncthreads();

  const int wave = tid >> 6, lane = tid & 63;
  const int m = lane & 15, quad = lane >> 4;
  float* tb = tbuf[wave];

  for (int nb = blockIdx.x * 64; nb < N; nb += gridDim.x * 64) {
    const int nBase = nb + wave * 16;
    int node = nBase + m;
    int nc = node < N ? node : N - 1;

    // A-frags: [h(hi,lo) | agg(hi)]
    short8 fhi[4], flo[2];
    fhi[0] = *(const short8*)(hhi + (long)nc * H + quad * 8);
    fhi[1] = *(const short8*)(hhi + (long)nc * H + 32 + quad * 8);
    flo[0] = *(const short8*)(hlo + (long)nc * H + quad * 8);
    flo[1] = *(const short8*)(hlo + (long)nc * H + 32 + quad * 8);
    fhi[2] = *(const short8*)(agg + (long)nc * H + quad * 8);
    fhi[3] = *(const short8*)(agg + (long)nc * H + 32 + quad * 8);

    // upd GEMM1 (K=128, weights hi-only)
    floatx4 acc[4];
#pragma unroll
    for (int t = 0; t < 4; ++t) acc[t] = (floatx4){0.f, 0.f, 0.f, 0.f};
#pragma unroll
    for (int t = 0; t < 4; ++t) {
      const short* wp = &u1h[(t * 16 + m) * PADU + quad * 8];
#pragma unroll
      for (int c = 0; c < 4; ++c) {
        acc[t] = MFMA(fhi[c], *(const short8*)(wp + 32 * c), acc[t]);
        if (c < 2) acc[t] = MFMA(flo[c], *(const short8*)(wp + 32 * c), acc[t]);
      }
    }

    // P -> tbuf -> A-frag (per-wave scratch; no block barrier needed)
#pragma unroll
    for (int t = 0; t < 4; ++t) {
      int col = t * 16 + m;
      float bb = b1s[col];
#pragma unroll
      for (int r = 0; r < 4; ++r)
        tb[(quad * 4 + r) * PADT + col] = fmaxf(acc[t][r] + bb, 0.f);
    }
    float av[16];
    *(floatx4*)(av + 0)  = *(const floatx4*)(&tb[m * PADT + quad * 8]);
    *(floatx4*)(av + 4)  = *(const floatx4*)(&tb[m * PADT + quad * 8 + 4]);
    *(floatx4*)(av + 8)  = *(const floatx4*)(&tb[m * PADT + 32 + quad * 8]);
    *(floatx4*)(av + 12) = *(const floatx4*)(&tb[m * PADT + 32 + quad * 8 + 4]);
    short8 thi[2], tlo[2];
#pragma unroll
    for (int j = 0; j < 8; ++j) {
      short hi, lo;
      split2(av[j], hi, lo);     thi[0][j] = hi; tlo[0][j] = lo;
      split2(av[8 + j], hi, lo); thi[1][j] = hi; tlo[1][j] = lo;
    }

    // upd GEMM2 (weights hi-only)
    floatx4 mac[4];
#pragma unroll
    for (int t = 0; t < 4; ++t) mac[t] = (floatx4){0.f, 0.f, 0.f, 0.f};
#pragma unroll
    for (int t = 0; t < 4; ++t) {
      const short* wp = &u2h[(t * 16 + m) * PADW + quad * 8];
#pragma unroll
      for (int c = 0; c < 2; ++c) {
        mac[t] = MFMA(thi[c], *(const short8*)(wp + 32 * c), mac[t]);
        mac[t] = MFMA(tlo[c], *(const short8*)(wp + 32 * c), mac[t]);
      }
    }

    // epilogue: BN + residual relu; write h planes; deposit h_new into tbuf
#pragma unroll
    for (int t = 0; t < 4; ++t) {
      int col = t * 16 + m;
      float bb = b2s[col], ss = scl[col], ff = sft[col];
#pragma unroll
      for (int r = 0; r < 4; ++r) {
        int nrow = nBase + quad * 4 + r;
        float hn = 0.f;
        if (nrow < N) {
          long el = (long)nrow * H + col;
          float hv = (mac[t][r] + bb) * ss + ff;
          float ho = bf2f(hhi[el]) + bf2f(hlo[el]);
          hn = fmaxf(hv + ho, 0.f);
          short hi2, lo2; split2(hn, hi2, lo2);
          hhi[el] = hi2; hlo[el] = lo2;
        }
        tb[(quad * 4 + r) * PADT + col] = hn;
      }
    }

    if (doMsg) {
      // h_new A-frag from tbuf
      *(floatx4*)(av + 0)  = *(const floatx4*)(&tb[m * PADT + quad * 8]);
      *(floatx4*)(av + 4)  = *(const floatx4*)(&tb[m * PADT + quad * 8 + 4]);
      *(floatx4*)(av + 8)  = *(const floatx4*)(&tb[m * PADT + 32 + quad * 8]);
      *(floatx4*)(av + 12) = *(const floatx4*)(&tb[m * PADT + 32 + quad * 8 + 4]);
#pragma unroll
      for (int j = 0; j < 8; ++j) {
        short hi, lo;
        split2(av[j], hi, lo);     thi[0][j] = hi; tlo[0][j] = lo;
        split2(av[8 + j], hi, lo); thi[1][j] = hi; tlo[1][j] = lo;
      }

      // msg GEMM1 (weights hi-only, h hi+lo)
#pragma unroll
      for (int t = 0; t < 4; ++t) acc[t] = (floatx4){0.f, 0.f, 0.f, 0.f};
#pragma unroll
      for (int t = 0; t < 4; ++t) {
        const short* wp = &m1h[(t * 16 + m) * PADW + quad * 8];
#pragma unroll
        for (int c = 0; c < 2; ++c) {
          acc[t] = MFMA(thi[c], *(const short8*)(wp + 32 * c), acc[t]);
          acc[t] = MFMA(tlo[c], *(const short8*)(wp + 32 * c), acc[t]);
        }
      }

#pragma unroll
      for (int t = 0; t < 4; ++t) {
        int col = t * 16 + m;
        float bb = mb1[col];
#pragma unroll
        for (int r = 0; r < 4; ++r)
          tb[(quad * 4 + r) * PADT + col] = fmaxf(acc[t][r] + bb, 0.f);
      }
      *(floatx4*)(av + 0)  = *(const floatx4*)(&tb[m * PADT + quad * 8]);
      *(floatx4*)(av + 4)  = *(const floatx4*)(&tb[m * PADT + quad * 8 + 4]);
      *(floatx4*)(av + 8)  = *(const floatx4*)(&tb[m * PADT + 32 + quad * 8]);
      *(floatx4*)(av + 12) = *(const floatx4*)(&tb[m * PADT + 32 + quad * 8 + 4]);
#pragma unroll
      for (int j = 0; j < 8; ++j) {
        short hi, lo;
        split2(av[j], hi, lo);     thi[0][j] = hi; tlo[0][j] = lo;
        split2(av[8 + j], hi, lo); thi[1][j] = hi; tlo[1][j] = lo;
      }

      // msg GEMM2 (weights hi-only)
#pragma unroll
      for (int t = 0; t < 4; ++t) mac[t] = (floatx4){0.f, 0.f, 0.f, 0.f};
#pragma unroll
      for (int t = 0; t < 4; ++t) {
        const short* wp = &m2h[(t * 16 + m) * PADW + quad * 8];
#pragma unroll
        for (int c = 0; c < 2; ++c) {
          mac[t] = MFMA(thi[c], *(const short8*)(wp + 32 * c), mac[t]);
          mac[t] = MFMA(tlo[c], *(const short8*)(wp + 32 * c), mac[t]);
        }
      }

#pragma unroll
      for (int t = 0; t < 4; ++t) {
        int col = t * 16 + m;
#pragma unroll
        for (int r = 0; r < 4; ++r) {
          int nrow = nBase + quad * 4 + r;
          if (nrow < N) Mout[(long)nrow * H + col] = f2bf(mac[t][r]);
        }
      }
    }
  }
}

// readout from hi/lo planes
__global__ __launch_bounds__(256) void k_out2(
    const short* __restrict__ hhi, const short* __restrict__ hlo,
    const void* __restrict__ W1, const void* __restrict__ B1,
    const void* __restrict__ W2, const void* __restrict__ B2,
    void* __restrict__ out, const int* __restrict__ flag, int NQ) {
  __shared__ float w1s[64 * 32];
  __shared__ float b1sh[32], w2s[32];
  bool isf32 = (*flag != 0);
  int tid = threadIdx.x;
  for (int idx = tid; idx < 2048; idx += 256) w1s[idx] = ldf(W1, idx, isf32);
  if (tid < 32) { b1sh[tid] = ldf(B1, tid, isf32); w2s[tid] = ldf(W2, tid, isf32); }
  __syncthreads();
  int v = blockIdx.x * 256 + tid;
  if (v >= NQ) return;
  float hr[64];
#pragma unroll
  for (int j = 0; j < 64; ++j)
    hr[j] = bf2f(hhi[(long)v * H + j]) + bf2f(hlo[(long)v * H + j]);
  float accum = ldf(B2, 0, isf32);
#pragma unroll 4
  for (int k = 0; k < 32; ++k) {
    float t = b1sh[k];
#pragma unroll
    for (int j = 0; j < 64; ++j) t += hr[j] * w1s[j * 32 + k];
    accum += fmaxf(t, 0.f) * w2s[k];
  }
  if (isf32) ((float*)out)[v] = accum;
  else ((short*)out)[v] = f2bf(accum);
}

extern "C" void kernel_launch(void* const* d_in, const int* in_sizes, int n_in,
                              void* d_out, int out_size, void* d_ws, size_t ws_size,
                              hipStream_t stream) {
  const void* x      = d_in[0];
  const int*  ei     = (const int*)d_in[1];
  const void* w_in   = d_in[3];
  const void* b_in   = d_in[4];
  const void* msg_w1 = d_in[5];
  const void* msg_b1 = d_in[6];
  const void* msg_w2 = d_in[7];
  const void* msg_b2 = d_in[8];
  const void* upd_w1 = d_in[9];
  const void* upd_b1 = d_in[10];
  const void* upd_w2 = d_in[11];
  const void* upd_b2 = d_in[12];
  const void* bn_g   = d_in[13];
  const void* bn_b   = d_in[14];
  const void* bn_m   = d_in[15];
  const void* bn_v   = d_in[16];
  const void* out_w1 = d_in[17];
  const void* out_b1 = d_in[18];
  const void* out_w2 = d_in[19];
  const void* out_b2 = d_in[20];

  const int N = in_sizes[0] / 3;
  const int E = in_sizes[1] / 2;
  const int L = in_sizes[5] / (H * H);
  const int* srcI = ei;
  const int* dstI = ei + E;

  // workspace layout (256B-aligned slots)
  size_t off = 0;
  auto alloc = [&](size_t bytes) { size_t o = off; off += (bytes + 255) & ~(size_t)255; return o; };
  size_t o_flag   = alloc(256);
  size_t o_hhi    = alloc((size_t)N * H * sizeof(short));
  size_t o_hlo    = alloc((size_t)N * H * sizeof(short));
  size_t o_agg    = alloc((size_t)N * H * sizeof(short));
  size_t o_M      = alloc((size_t)N * H * sizeof(short));
  size_t o_rowptr = alloc((size_t)(N + 1) * sizeof(int));
  size_t o_cursor = alloc((size_t)N * sizeof(int));
  size_t o_bsum   = alloc(256 * sizeof(int));
  size_t o_bexcl  = alloc(256 * sizeof(int));
  size_t o_srcS   = alloc((size_t)E * sizeof(int));
  const int NB = (N + 1023) >> 10;

  char* ws = (char*)d_ws;
  int*   flag   = (int*)(ws + o_flag);
  short* hhi    = (short*)(ws + o_hhi);
  short* hlo    = (short*)(ws + o_hlo);
  short* aggS   = (short*)(ws + o_agg);
  short* Mbuf   = (short*)(ws + o_M);
  int*   rowptr = (int*)(ws + o_rowptr);
  int*   deg    = (int*)(ws + o_cursor);
  int*   bsum   = (int*)(ws + o_bsum);
  int*   bexcl  = (int*)(ws + o_bexcl);
  int*   srcS   = (int*)(ws + o_srcS);

  k_probe<<<1, 256, 0, stream>>>((const short*)x, flag);
  k_input2<<<(N * H + 255) / 256, 256, 0, stream>>>(x, w_in, b_in, hhi, hlo, flag, N);

  // CSR build, XCD-partitioned
  hipMemsetAsync(deg, 0, (size_t)N * sizeof(int), stream);
  k_hist_x<<<8 * 128, 256, 0, stream>>>(dstI, deg, E, N);
  k_scan_local<<<NB, 256, 0, stream>>>(deg, rowptr, bsum, N);
  k_scan_block<<<1, 256, 0, stream>>>(bsum, bexcl, NB);
  k_scan_add<<<(N + 256) / 256, 256, 0, stream>>>(rowptr, deg, bexcl, N, E);
  k_scatter_x<<<8 * 128, 256, 0, stream>>>(srcI, dstI, deg, srcS, E, N);

  // M_0 (full-precision standalone MLP, persistent)
  k_mlp<<<768, 256, 0, stream>>>(hhi, hlo,
      msg_w1, msg_b1, msg_w2, 0, 0, Mbuf, flag, N);

  const int GB = 2048;
  const int UB = 512;  // persistent k_updm blocks: 2/CU (LDS ~70KB)
  for (int i = 0; i < L; ++i) {
    long oW = (long)i * H * H, oU = (long)i * 2 * H * H, oB = (long)i * H;
    int doMsg = (i + 1 < L) ? 1 : 0;
    long oWn = doMsg ? (long)(i + 1) * H * H : 0;
    long oBn = doMsg ? (long)(i + 1) * H : 0;
    k_gather<<<GB, 256, 0, stream>>>(Mbuf, rowptr, srcS,
        msg_b2, oB, aggS, flag, N, GB * 4);
    k_updm<<<UB, 256, 0, stream>>>(hhi, hlo, aggS,
        upd_w1, upd_b1, upd_w2, upd_b2, bn_g, bn_b, bn_m, bn_v,
        msg_w1, msg_b1, msg_w2,
        oU, oW, oB, oWn, oBn, Mbuf, flag, N, doMsg);
  }
  k_out2<<<(out_size + 255) / 256, 256, 0, stream>>>(hhi, hlo,
      out_w1, out_b1, out_w2, out_b2, d_out, flag, out_size);
}